// Round 4
// baseline (1234.202 us; speedup 1.0000x reference)
//
#include <hip/hip_runtime.h>
#include <hip/hip_bf16.h>

// f32 in/out. Gather-fed intermediates (x0,h1,h2,g3) stored bf16 (f32 accum).
// CSR built via 2-level bucket sort (dst>>6) for write locality: the old
// one-shot atomic scatter did random 4B writes -> 163MB WRITE_SIZE for a
// 9.6MB array (write-allocate line waste). Bucketed scatter keeps concurrent
// writes adjacent -> lines fill before writeback.

typedef unsigned short u16;
typedef unsigned int   u32;

__device__ __forceinline__ float b2f(u16 u){
  union { u32 i; float f; } c; c.i = ((u32)u) << 16; return c.f;
}
__device__ __forceinline__ u16 f2b(float f){
  union { float f; u32 i; } c; c.f = f;
  u32 x = c.i;
  u32 r = x + 0x7FFFu + ((x >> 16) & 1u);   // round-to-nearest-even
  return (u16)(r >> 16);
}

// ---------------- graph preprocessing: bucketed CSR build ----------------
// bucket b = dst >> 6 (64 nodes per bucket). packed edge = (dst&63)<<18 | src
// (src < 2^18). K = ceil(N/64).

__global__ __launch_bounds__(256) void k_hist(const int* __restrict__ dst, int ne, int K,
                                              u32* __restrict__ bhist){
  extern __shared__ u32 sh[];
  int t = threadIdx.x;
  for (int i = t; i < K; i += 256) sh[i] = 0;
  __syncthreads();
  for (int i = blockIdx.x*256 + t; i < ne; i += gridDim.x*256)
    atomicAdd(&sh[dst[i] >> 6], 1u);
  __syncthreads();
  for (int i = t; i < K; i += 256){
    u32 v = sh[i];
    if (v) atomicAdd(&bhist[i], v);
  }
}

// single block: exclusive scan of bhist[K] -> bbase[K+1], bcur[K]=base
__global__ __launch_bounds__(256) void k_scanB(const u32* __restrict__ bhist, int K,
                                               u32* __restrict__ bbase, u32* __restrict__ bcur){
  __shared__ u32 s[256];
  int t = threadIdx.x;
  int items = (K + 255) / 256;           // <=16 for this problem size
  u32 local[16];
  int s0 = t * items;
  u32 sum = 0;
  for (int j = 0; j < items; j++){
    int idx = s0 + j;
    u32 v = (idx < K) ? bhist[idx] : 0;
    local[j] = v; sum += v;
  }
  s[t] = sum; __syncthreads();
  for (int off = 1; off < 256; off <<= 1){
    u32 add = (t >= off) ? s[t-off] : 0;
    __syncthreads();
    s[t] += add;
    __syncthreads();
  }
  u32 run = s[t] - sum;                  // exclusive prefix
  for (int j = 0; j < items; j++){
    int idx = s0 + j;
    if (idx < K){ bbase[idx] = run; bcur[idx] = run; }
    run += local[j];
  }
  if (t == 255) bbase[K] = s[255];
}

__global__ __launch_bounds__(256) void k_bucket(const int* __restrict__ src, const int* __restrict__ dst,
                                                int ne, u32* __restrict__ bcur, u32* __restrict__ ebuf){
  int i = blockIdx.x*256 + threadIdx.x;
  if (i < ne){
    int d = dst[i];
    u32 p = atomicAdd(&bcur[d >> 6], 1u);
    ebuf[p] = ((u32)(d & 63) << 18) | (u32)src[i];
  }
}

// one block per bucket: per-node counts -> row_ptr + r, then local scatter -> col
__global__ __launch_bounds__(256) void k_csr(const u32* __restrict__ ebuf, const u32* __restrict__ bbase,
                                             int n, int ne, int* __restrict__ row_ptr,
                                             float* __restrict__ r, int* __restrict__ col){
  __shared__ u32 cnt[64];
  __shared__ u32 pfx[64];
  __shared__ u32 cur[64];
  int b = blockIdx.x, t = threadIdx.x;
  u32 bb = bbase[b], be = bbase[b+1];
  int nbase = b << 6;
  int nn = n - nbase; if (nn > 64) nn = 64;
  if (t < 64) cnt[t] = 0;
  __syncthreads();
  for (u32 e = bb + t; e < be; e += 256)
    atomicAdd(&cnt[ebuf[e] >> 18], 1u);
  __syncthreads();
  if (t < 64) pfx[t] = cnt[t];
  __syncthreads();
  for (int off = 1; off < 64; off <<= 1){
    u32 add = (t < 64 && t >= off) ? pfx[t-off] : 0;
    __syncthreads();
    if (t < 64) pfx[t] += add;
    __syncthreads();
  }
  if (t < 64){
    u32 excl = pfx[t] - cnt[t];
    cur[t] = bb + excl;
    if (t < nn){
      row_ptr[nbase + t] = (int)(bb + excl);
      r[nbase + t] = rsqrtf(fmaxf((float)cnt[t], 1.0f));
    }
  }
  __syncthreads();
  for (u32 e = bb + t; e < be; e += 256){
    u32 v = ebuf[e];
    u32 p = atomicAdd(&cur[v >> 18], 1u);
    col[p] = (int)(v & 0x3FFFFu);
  }
  if (b == 0 && t == 0) row_ptr[n] = ne;
}

// x0[n,64] (bf16) = concat(ut,it)[n,:] * r[n]
__global__ __launch_bounds__(256) void k_scale0(const float* __restrict__ ut, const float* __restrict__ it,
    const float* __restrict__ r, u16* __restrict__ x0, int n, int nu){
  int i = blockIdx.x*256 + threadIdx.x;
  int base = i*4;
  if (base < n*64){
    int node = base >> 6;
    float rv = r[node];
    const float* srcp = (node < nu) ? (ut + (size_t)node*64) : (it + (size_t)(node-nu)*64);
    float4 v = *(const float4*)(srcp + (base & 63));
    ushort4 o;
    o.x = f2b(v.x*rv); o.y = f2b(v.y*rv); o.z = f2b(v.z*rv); o.w = f2b(v.w*rv);
    *(ushort4*)(x0 + base) = o;
  }
}

// ---------------- aggregation (one wave per node, half-wave edge split) ----------------

__global__ __launch_bounds__(256) void k_agg1(const u16* __restrict__ x0, const float* __restrict__ r,
    const int* __restrict__ row_ptr, const int* __restrict__ col, float* __restrict__ out, int n){
  int wid = (blockIdx.x*256 + threadIdx.x) >> 6;
  int lane = threadIdx.x & 63;
  if (wid >= n) return;
  int half = lane >> 5, l = lane & 31;
  int beg = row_ptr[wid], end = row_ptr[wid+1];
  float ax = 0.f, ay = 0.f;
  for (int e = beg + half; e < end; e += 2){
    int s = col[e];
    u32 u = *(const u32*)(x0 + (size_t)s*64 + l*2);
    ax += b2f((u16)(u & 0xffff));
    ay += b2f((u16)(u >> 16));
  }
  ax += __shfl_xor(ax, 32);
  ay += __shfl_xor(ay, 32);
  if (half == 0){
    float rn = r[wid];
    ((float2*)out)[(size_t)wid*32 + l] = make_float2(ax*rn, ay*rn);
  }
}

__global__ __launch_bounds__(256) void k_agg128(const u16* __restrict__ h, const float* __restrict__ r,
    const int* __restrict__ row_ptr, const int* __restrict__ col, float* __restrict__ out, int n){
  int wid = (blockIdx.x*256 + threadIdx.x) >> 6;
  int lane = threadIdx.x & 63;
  if (wid >= n) return;
  int half = lane >> 5, l = lane & 31;
  int beg = row_ptr[wid], end = row_ptr[wid+1];
  float a0=0.f, a1=0.f, a2=0.f, a3=0.f;
  for (int e = beg + half; e < end; e += 2){
    int s = col[e];
    uint2 u = *(const uint2*)(h + (size_t)s*128 + l*4);
    a0 += b2f((u16)(u.x & 0xffff));
    a1 += b2f((u16)(u.x >> 16));
    a2 += b2f((u16)(u.y & 0xffff));
    a3 += b2f((u16)(u.y >> 16));
  }
  a0 += __shfl_xor(a0, 32);
  a1 += __shfl_xor(a1, 32);
  a2 += __shfl_xor(a2, 32);
  a3 += __shfl_xor(a3, 32);
  if (half == 0){
    float rn = r[wid];
    ((float4*)out)[(size_t)wid*32 + l] = make_float4(a0*rn, a1*rn, a2*rn, a3*rn);
  }
}

__global__ __launch_bounds__(256) void k_agg64b(const u16* __restrict__ g, const float* __restrict__ r,
    const int* __restrict__ row_ptr, const int* __restrict__ col, const float* __restrict__ b3,
    float* __restrict__ out, int n){
  int wid = (blockIdx.x*256 + threadIdx.x) >> 6;
  int lane = threadIdx.x & 63;
  if (wid >= n) return;
  int half = lane >> 5, l = lane & 31;
  int beg = row_ptr[wid], end = row_ptr[wid+1];
  float ax = 0.f, ay = 0.f;
  for (int e = beg + half; e < end; e += 2){
    int s = col[e];
    u32 u = *(const u32*)(g + (size_t)s*64 + l*2);
    ax += b2f((u16)(u & 0xffff));
    ay += b2f((u16)(u >> 16));
  }
  ax += __shfl_xor(ax, 32);
  ay += __shfl_xor(ay, 32);
  if (half == 0){
    float rn = r[wid];
    float2 bb = ((const float2*)b3)[l];
    ((float2*)out)[(size_t)wid*32 + l] = make_float2(ax*rn + bb.x, ay*rn + bb.y);
  }
}

// ---------------- tiled f32-math GEMM: C = act(A @ W + b) * r ----------------
template<int IN, int OUT, bool BIAS, bool RELU, bool SCALE, bool GATHER, bool DOTEP,
         bool ABF, bool CBF>
__global__ __launch_bounds__(256) void k_gemm(
    const void* __restrict__ Ap, const float* __restrict__ W, const float* __restrict__ bias,
    const float* __restrict__ rr, void* __restrict__ Cp, int nrows, int nu,
    const int* __restrict__ uidx, const int* __restrict__ vidx,
    const float* __restrict__ P3, const float* __restrict__ pb3, float* __restrict__ outp)
{
  constexpr int CPT = OUT/32;
  __shared__ float At[64][68];
  __shared__ float Wt[64*OUT];
  const int t  = threadIdx.x;
  const int tx = t & 31, ty = t >> 5;
  const int base = blockIdx.x * 64;

  float acc[8][CPT];
#pragma unroll
  for (int i=0;i<8;i++)
#pragma unroll
    for (int j=0;j<CPT;j++) acc[i][j] = 0.f;

  for (int kt = 0; kt < IN; kt += 64){
#pragma unroll
    for (int q=0;q<4;q++){
      int f = t + 256*q;
      int row = f >> 4;
      int k4  = (f & 15) << 2;
      int gr  = base + row;
      float4 a = make_float4(0.f,0.f,0.f,0.f);
      if (gr < nrows){
        if constexpr (ABF){
          const u16* Ab = (const u16*)Ap;
          ushort4 v = *(const ushort4*)(Ab + (size_t)gr*IN + kt + k4);
          a = make_float4(b2f(v.x), b2f(v.y), b2f(v.z), b2f(v.w));
        } else {
          const float* Af = (const float*)Ap;
          const float* ap;
          if constexpr (GATHER){
            int node = (kt == 0) ? uidx[gr] : (nu + vidx[gr]);
            ap = Af + (size_t)node*64 + k4;
          } else {
            ap = Af + (size_t)gr*IN + kt + k4;
          }
          a = *(const float4*)ap;
        }
      }
      At[k4+0][row] = a.x; At[k4+1][row] = a.y; At[k4+2][row] = a.z; At[k4+3][row] = a.w;
    }
    for (int f = t; f < 64*OUT; f += 256){
      Wt[f] = W[(size_t)kt*OUT + f];
    }
    __syncthreads();

#pragma unroll 16
    for (int k=0;k<64;k++){
      const float4 a0 = *(const float4*)&At[k][ty*8];
      const float4 a1 = *(const float4*)&At[k][ty*8+4];
      float ar[8] = {a0.x,a0.y,a0.z,a0.w,a1.x,a1.y,a1.z,a1.w};
      float bv[CPT];
      if constexpr (CPT == 4){
        float4 b4 = *(const float4*)&Wt[k*OUT + tx*4];
        bv[0]=b4.x; bv[1]=b4.y; bv[2]=b4.z; bv[3]=b4.w;
      } else if constexpr (CPT == 2){
        float2 b2 = *(const float2*)&Wt[k*OUT + tx*2];
        bv[0]=b2.x; bv[1]=b2.y;
      } else {
        bv[0] = Wt[k*OUT + tx];
      }
#pragma unroll
      for (int i=0;i<8;i++)
#pragma unroll
        for (int j=0;j<CPT;j++)
          acc[i][j] = fmaf(ar[i], bv[j], acc[i][j]);
    }
    __syncthreads();
  }

  if constexpr (!DOTEP){
#pragma unroll
    for (int i=0;i<8;i++){
      int gr = base + ty*8 + i;
      if (gr < nrows){
        float rs = 1.f;
        if constexpr (SCALE) rs = rr[gr];
        float v[CPT];
#pragma unroll
        for (int j=0;j<CPT;j++){
          float x = acc[i][j];
          if constexpr (BIAS) x += bias[tx*CPT + j];
          if constexpr (RELU) x = fmaxf(x, 0.f);
          if constexpr (SCALE) x *= rs;
          v[j] = x;
        }
        if constexpr (CBF){
          u16* Cb = (u16*)Cp;
          if constexpr (CPT == 4){
            ushort4 o; o.x=f2b(v[0]); o.y=f2b(v[1]); o.z=f2b(v[2]); o.w=f2b(v[3]);
            *(ushort4*)(Cb + (size_t)gr*OUT + tx*4) = o;
          } else if constexpr (CPT == 2){
            ushort2 o; o.x=f2b(v[0]); o.y=f2b(v[1]);
            *(ushort2*)(Cb + (size_t)gr*OUT + tx*2) = o;
          } else {
            Cb[(size_t)gr*OUT + tx] = f2b(v[0]);
          }
        } else {
          float* Cf = (float*)Cp;
#pragma unroll
          for (int j=0;j<CPT;j++) Cf[(size_t)gr*OUT + tx*CPT + j] = v[j];
        }
      }
    }
  } else {
    float p3 = P3[tx];
    float pb = pb3[0];
    float bb = bias[tx];
#pragma unroll
    for (int i=0;i<8;i++){
      float v = fmaxf(acc[i][0] + bb, 0.f);
      float part = v * p3;
      part += __shfl_xor(part, 16);
      part += __shfl_xor(part, 8);
      part += __shfl_xor(part, 4);
      part += __shfl_xor(part, 2);
      part += __shfl_xor(part, 1);
      int gr = base + ty*8 + i;
      if (tx == 0 && gr < nrows){
        outp[gr] = 1.f / (1.f + __expf(-(part + pb)));
      }
    }
  }
}

// ---------------- launcher ----------------

extern "C" void kernel_launch(void* const* d_in, const int* in_sizes, int n_in,
                              void* d_out, int out_size, void* d_ws, size_t ws_size,
                              hipStream_t stream){
  const float* ut  = (const float*)d_in[0];
  const float* it  = (const float*)d_in[1];
  const float* W1  = (const float*)d_in[2];
  const float* b1  = (const float*)d_in[3];
  const float* W2  = (const float*)d_in[4];
  const float* b2  = (const float*)d_in[5];
  const float* W3  = (const float*)d_in[6];
  const float* b3  = (const float*)d_in[7];
  const float* P1  = (const float*)d_in[8];
  const float* pb1 = (const float*)d_in[9];
  const float* P2  = (const float*)d_in[10];
  const float* pb2 = (const float*)d_in[11];
  const float* P3  = (const float*)d_in[12];
  const float* pb3 = (const float*)d_in[13];
  const int* src  = (const int*)d_in[14];
  const int* dst  = (const int*)d_in[15];
  const int* uidx = (const int*)d_in[16];
  const int* vidx = (const int*)d_in[17];

  const int NU = in_sizes[0] / 64;
  const int NI = in_sizes[1] / 64;
  const int N  = NU + NI;
  const int NE = in_sizes[14];
  const int B  = in_sizes[16];
  const int K  = (N + 63) >> 6;          // buckets of 64 nodes

  char* w = (char*)d_ws;
  auto alloc = [&](size_t bytes)->void*{
    void* p = (void*)w;
    w += (bytes + 255) & ~(size_t)255;
    return p;
  };
  float* r       = (float*)alloc((size_t)N*4);
  int*   row_ptr = (int*)  alloc((size_t)(N+1)*4);
  u32*   bhist   = (u32*)  alloc((size_t)K*4);
  u32*   bbase   = (u32*)  alloc((size_t)(K+1)*4);
  u32*   bcur    = (u32*)  alloc((size_t)K*4);
  int*   col     = (int*)  alloc((size_t)NE*4);
  float* bufA    = (float*)alloc((size_t)N*128*4);   // ebuf (pre) -> m2 (f32) -> A1
  float* bufB    = (float*)alloc((size_t)N*64*4);    // m1 (f32) -> x3 (f32)
  u16*   bufC    = (u16*)  alloc((size_t)N*128*2);   // h1 (bf16) -> h2 (bf16)
  u16*   bufD    = (u16*)  alloc((size_t)N*64*2);    // x0 (bf16) -> g3 (bf16)
  if ((size_t)(w - (char*)d_ws) > ws_size) return;

  u32* ebuf = (u32*)bufA;  // dead before k_agg128 writes m2

  hipMemsetAsync(bhist, 0, (size_t)K*4, stream);

  int g;
  k_hist  <<<128, 256, (size_t)K*4, stream>>>(dst, NE, K, bhist);
  k_scanB <<<1, 256, 0, stream>>>(bhist, K, bbase, bcur);
  g = (NE + 255)/256; k_bucket<<<g,256,0,stream>>>(src, dst, NE, bcur, ebuf);
  k_csr   <<<K, 256, 0, stream>>>(ebuf, bbase, N, NE, row_ptr, r, col);

  const int ga = (N + 3)/4;     // 4 waves (nodes) per block
  const int gb = (N + 63)/64;
  const int gm = (B + 63)/64;

  u16* x0 = bufD;
  g = (N*64/4 + 255)/256; k_scale0<<<g,256,0,stream>>>(ut, it, r, x0, N, NU);

  float* m1 = bufB;
  k_agg1<<<ga,256,0,stream>>>(x0, r, row_ptr, col, m1, N);
  u16* h1 = bufC;
  k_gemm<64,128,true,true,true,false,false,false,true><<<gb,256,0,stream>>>(
      m1, W1, b1, r, h1, N, NU, nullptr, nullptr, nullptr, nullptr, nullptr);

  float* m2 = bufA;               // ebuf dead from here
  k_agg128<<<ga,256,0,stream>>>(h1, r, row_ptr, col, m2, N);
  u16* h2 = bufC;
  k_gemm<128,128,true,true,true,false,false,false,true><<<gb,256,0,stream>>>(
      m2, W2, b2, r, h2, N, NU, nullptr, nullptr, nullptr, nullptr, nullptr);

  u16* g3 = bufD;
  k_gemm<128,64,false,false,false,false,false,true,true><<<gb,256,0,stream>>>(
      h2, W3, nullptr, nullptr, g3, N, NU, nullptr, nullptr, nullptr, nullptr, nullptr);

  float* x3 = bufB;
  k_agg64b<<<ga,256,0,stream>>>(g3, r, row_ptr, col, b3, x3, N);

  float* A1 = bufA;
  k_gemm<128,64,true,true,false,true,false,false,false><<<gm,256,0,stream>>>(
      x3, P1, pb1, nullptr, A1, B, NU, uidx, vidx, nullptr, nullptr, nullptr);

  k_gemm<64,32,true,true,false,false,true,false,false><<<gm,256,0,stream>>>(
      A1, P2, pb2, nullptr, nullptr, B, NU, nullptr, nullptr, P3, pb3, (float*)d_out);
}

// Round 5
// 886.233 us; speedup vs baseline: 1.3926x; 1.3926x over previous
//
#include <hip/hip_runtime.h>
#include <hip/hip_bf16.h>

// f32 in/out. Gather-fed intermediates (x0,h1,h2,g3) stored bf16 (f32 accum).
// CSR build: block-aggregated bucket scatter. Round-4 lesson: per-edge global
// atomics on 2344 cursors serialize (~400ns/op on a hot line) -> 397us. Fix:
// LDS histogram per 4096-edge block, ONE reservation atomic per (block,bin),
// then LDS-cursor scatter -> ~7-edge contiguous runs, ~343K spread atomics.

typedef unsigned short u16;
typedef unsigned int   u32;

__device__ __forceinline__ float b2f(u16 u){
  union { u32 i; float f; } c; c.i = ((u32)u) << 16; return c.f;
}
__device__ __forceinline__ u16 f2b(float f){
  union { float f; u32 i; } c; c.f = f;
  u32 x = c.i;
  u32 r = x + 0x7FFFu + ((x >> 16) & 1u);   // round-to-nearest-even
  return (u16)(r >> 16);
}

// ---------------- graph preprocessing: aggregated bucket scatter ----------------
// bucket b = dst >> 8 (256 nodes per bucket), K = ceil(N/256).
// packed edge = (dst&255)<<18 | src   (src < 2^18, 26 bits total).

__global__ __launch_bounds__(256) void k_histK(const int* __restrict__ dst, int ne, int K,
                                               u32* __restrict__ bhist){
  extern __shared__ u32 sh[];
  int t = threadIdx.x;
  for (int i = t; i < K; i += 256) sh[i] = 0;
  __syncthreads();
  for (int i = blockIdx.x*256 + t; i < ne; i += gridDim.x*256)
    atomicAdd(&sh[dst[i] >> 8], 1u);
  __syncthreads();
  int rot = (int)((blockIdx.x * 73u) % (u32)K);     // stagger hot-line bursts
  for (int jj = t; jj < K; jj += 256){
    int i = jj + rot; if (i >= K) i -= K;
    u32 v = sh[i];
    if (v) atomicAdd(&bhist[i], v);
  }
}

// single block: exclusive scan of bhist[K] -> bbase[K+1], gcur[K]=base
__global__ __launch_bounds__(256) void k_scanK(const u32* __restrict__ bhist, int K,
                                               u32* __restrict__ bbase, u32* __restrict__ gcur){
  __shared__ u32 s[256];
  int t = threadIdx.x;
  int items = (K + 255) / 256;           // <=16
  u32 local[16];
  int s0 = t * items;
  u32 sum = 0;
  for (int j = 0; j < items; j++){
    int idx = s0 + j;
    u32 v = (idx < K) ? bhist[idx] : 0;
    local[j] = v; sum += v;
  }
  s[t] = sum; __syncthreads();
  for (int off = 1; off < 256; off <<= 1){
    u32 add = (t >= off) ? s[t-off] : 0;
    __syncthreads();
    s[t] += add;
    __syncthreads();
  }
  u32 run = s[t] - sum;                  // exclusive prefix
  for (int j = 0; j < items; j++){
    int idx = s0 + j;
    if (idx < K){ bbase[idx] = run; gcur[idx] = run; }
    run += local[j];
  }
  if (t == 255) bbase[K] = s[255];
}

// 4096 edges per block: LDS hist -> one reservation atomic per touched bin ->
// LDS-cursor scatter (runs of ~7 consecutive u32 per (block,bin)).
__global__ __launch_bounds__(256) void k_scatterR(const int* __restrict__ src, const int* __restrict__ dst,
                                                  int ne, int K, u32* __restrict__ gcur,
                                                  u32* __restrict__ ebuf){
  extern __shared__ u32 cnt[];           // [K] counts, then reused as cursors
  int t = threadIdx.x;
  int e0 = blockIdx.x * 4096;
  for (int i = t; i < K; i += 256) cnt[i] = 0;
  __syncthreads();
#pragma unroll
  for (int j = 0; j < 16; j++){
    int e = e0 + j*256 + t;
    if (e < ne) atomicAdd(&cnt[dst[e] >> 8], 1u);
  }
  __syncthreads();
  int rot = (int)((blockIdx.x * 73u) % (u32)K);
  for (int jj = t; jj < K; jj += 256){
    int i = jj + rot; if (i >= K) i -= K;
    u32 c = cnt[i];
    if (c) cnt[i] = atomicAdd(&gcur[i], c);   // reserve run; cnt becomes cursor
  }
  __syncthreads();
#pragma unroll
  for (int j = 0; j < 16; j++){
    int e = e0 + j*256 + t;
    if (e < ne){
      int d = dst[e];
      u32 p = atomicAdd(&cnt[d >> 8], 1u);
      ebuf[p] = ((u32)(d & 255) << 18) | (u32)src[e];
    }
  }
}

// one block per bucket: per-node counts -> row_ptr + r, then local scatter -> col
__global__ __launch_bounds__(256) void k_csr(const u32* __restrict__ ebuf, const u32* __restrict__ bbase,
                                             int n, int ne, int* __restrict__ row_ptr,
                                             float* __restrict__ r, int* __restrict__ col){
  __shared__ u32 cnt[256];
  __shared__ u32 pfx[256];
  __shared__ u32 cur[256];
  int b = blockIdx.x, t = threadIdx.x;
  u32 bb = bbase[b], be = bbase[b+1];
  int nbase = b << 8;
  int nn = n - nbase; if (nn > 256) nn = 256;
  cnt[t] = 0;
  __syncthreads();
  for (u32 e = bb + t; e < be; e += 256)
    atomicAdd(&cnt[ebuf[e] >> 18], 1u);
  __syncthreads();
  pfx[t] = cnt[t];
  __syncthreads();
  for (int off = 1; off < 256; off <<= 1){
    u32 add = (t >= off) ? pfx[t-off] : 0;
    __syncthreads();
    pfx[t] += add;
    __syncthreads();
  }
  u32 excl = pfx[t] - cnt[t];
  cur[t] = bb + excl;
  if (t < nn){
    row_ptr[nbase + t] = (int)(bb + excl);
    r[nbase + t] = rsqrtf(fmaxf((float)cnt[t], 1.0f));
  }
  __syncthreads();
  for (u32 e = bb + t; e < be; e += 256){
    u32 v = ebuf[e];
    u32 p = atomicAdd(&cur[v >> 18], 1u);
    col[p] = (int)(v & 0x3FFFFu);
  }
  if (b == 0 && t == 0) row_ptr[n] = ne;
}

// x0[n,64] (bf16) = concat(ut,it)[n,:] * r[n]
__global__ __launch_bounds__(256) void k_scale0(const float* __restrict__ ut, const float* __restrict__ it,
    const float* __restrict__ r, u16* __restrict__ x0, int n, int nu){
  int i = blockIdx.x*256 + threadIdx.x;
  int base = i*4;
  if (base < n*64){
    int node = base >> 6;
    float rv = r[node];
    const float* srcp = (node < nu) ? (ut + (size_t)node*64) : (it + (size_t)(node-nu)*64);
    float4 v = *(const float4*)(srcp + (base & 63));
    ushort4 o;
    o.x = f2b(v.x*rv); o.y = f2b(v.y*rv); o.z = f2b(v.z*rv); o.w = f2b(v.w*rv);
    *(ushort4*)(x0 + base) = o;
  }
}

// ---------------- aggregation (one wave per node, half-wave edge split) ----------------

__global__ __launch_bounds__(256) void k_agg1(const u16* __restrict__ x0, const float* __restrict__ r,
    const int* __restrict__ row_ptr, const int* __restrict__ col, float* __restrict__ out, int n){
  int wid = (blockIdx.x*256 + threadIdx.x) >> 6;
  int lane = threadIdx.x & 63;
  if (wid >= n) return;
  int half = lane >> 5, l = lane & 31;
  int beg = row_ptr[wid], end = row_ptr[wid+1];
  float ax = 0.f, ay = 0.f;
  for (int e = beg + half; e < end; e += 2){
    int s = col[e];
    u32 u = *(const u32*)(x0 + (size_t)s*64 + l*2);
    ax += b2f((u16)(u & 0xffff));
    ay += b2f((u16)(u >> 16));
  }
  ax += __shfl_xor(ax, 32);
  ay += __shfl_xor(ay, 32);
  if (half == 0){
    float rn = r[wid];
    ((float2*)out)[(size_t)wid*32 + l] = make_float2(ax*rn, ay*rn);
  }
}

__global__ __launch_bounds__(256) void k_agg128(const u16* __restrict__ h, const float* __restrict__ r,
    const int* __restrict__ row_ptr, const int* __restrict__ col, float* __restrict__ out, int n){
  int wid = (blockIdx.x*256 + threadIdx.x) >> 6;
  int lane = threadIdx.x & 63;
  if (wid >= n) return;
  int half = lane >> 5, l = lane & 31;
  int beg = row_ptr[wid], end = row_ptr[wid+1];
  float a0=0.f, a1=0.f, a2=0.f, a3=0.f;
  for (int e = beg + half; e < end; e += 2){
    int s = col[e];
    uint2 u = *(const uint2*)(h + (size_t)s*128 + l*4);
    a0 += b2f((u16)(u.x & 0xffff));
    a1 += b2f((u16)(u.x >> 16));
    a2 += b2f((u16)(u.y & 0xffff));
    a3 += b2f((u16)(u.y >> 16));
  }
  a0 += __shfl_xor(a0, 32);
  a1 += __shfl_xor(a1, 32);
  a2 += __shfl_xor(a2, 32);
  a3 += __shfl_xor(a3, 32);
  if (half == 0){
    float rn = r[wid];
    ((float4*)out)[(size_t)wid*32 + l] = make_float4(a0*rn, a1*rn, a2*rn, a3*rn);
  }
}

__global__ __launch_bounds__(256) void k_agg64b(const u16* __restrict__ g, const float* __restrict__ r,
    const int* __restrict__ row_ptr, const int* __restrict__ col, const float* __restrict__ b3,
    float* __restrict__ out, int n){
  int wid = (blockIdx.x*256 + threadIdx.x) >> 6;
  int lane = threadIdx.x & 63;
  if (wid >= n) return;
  int half = lane >> 5, l = lane & 31;
  int beg = row_ptr[wid], end = row_ptr[wid+1];
  float ax = 0.f, ay = 0.f;
  for (int e = beg + half; e < end; e += 2){
    int s = col[e];
    u32 u = *(const u32*)(g + (size_t)s*64 + l*2);
    ax += b2f((u16)(u & 0xffff));
    ay += b2f((u16)(u >> 16));
  }
  ax += __shfl_xor(ax, 32);
  ay += __shfl_xor(ay, 32);
  if (half == 0){
    float rn = r[wid];
    float2 bb = ((const float2*)b3)[l];
    ((float2*)out)[(size_t)wid*32 + l] = make_float2(ax*rn + bb.x, ay*rn + bb.y);
  }
}

// ---------------- tiled f32-math GEMM: C = act(A @ W + b) * r ----------------
template<int IN, int OUT, bool BIAS, bool RELU, bool SCALE, bool GATHER, bool DOTEP,
         bool ABF, bool CBF>
__global__ __launch_bounds__(256) void k_gemm(
    const void* __restrict__ Ap, const float* __restrict__ W, const float* __restrict__ bias,
    const float* __restrict__ rr, void* __restrict__ Cp, int nrows, int nu,
    const int* __restrict__ uidx, const int* __restrict__ vidx,
    const float* __restrict__ P3, const float* __restrict__ pb3, float* __restrict__ outp)
{
  constexpr int CPT = OUT/32;
  __shared__ float At[64][68];
  __shared__ float Wt[64*OUT];
  const int t  = threadIdx.x;
  const int tx = t & 31, ty = t >> 5;
  const int base = blockIdx.x * 64;

  float acc[8][CPT];
#pragma unroll
  for (int i=0;i<8;i++)
#pragma unroll
    for (int j=0;j<CPT;j++) acc[i][j] = 0.f;

  for (int kt = 0; kt < IN; kt += 64){
#pragma unroll
    for (int q=0;q<4;q++){
      int f = t + 256*q;
      int row = f >> 4;
      int k4  = (f & 15) << 2;
      int gr  = base + row;
      float4 a = make_float4(0.f,0.f,0.f,0.f);
      if (gr < nrows){
        if constexpr (ABF){
          const u16* Ab = (const u16*)Ap;
          ushort4 v = *(const ushort4*)(Ab + (size_t)gr*IN + kt + k4);
          a = make_float4(b2f(v.x), b2f(v.y), b2f(v.z), b2f(v.w));
        } else {
          const float* Af = (const float*)Ap;
          const float* ap;
          if constexpr (GATHER){
            int node = (kt == 0) ? uidx[gr] : (nu + vidx[gr]);
            ap = Af + (size_t)node*64 + k4;
          } else {
            ap = Af + (size_t)gr*IN + kt + k4;
          }
          a = *(const float4*)ap;
        }
      }
      At[k4+0][row] = a.x; At[k4+1][row] = a.y; At[k4+2][row] = a.z; At[k4+3][row] = a.w;
    }
    for (int f = t; f < 64*OUT; f += 256){
      Wt[f] = W[(size_t)kt*OUT + f];
    }
    __syncthreads();

#pragma unroll 16
    for (int k=0;k<64;k++){
      const float4 a0 = *(const float4*)&At[k][ty*8];
      const float4 a1 = *(const float4*)&At[k][ty*8+4];
      float ar[8] = {a0.x,a0.y,a0.z,a0.w,a1.x,a1.y,a1.z,a1.w};
      float bv[CPT];
      if constexpr (CPT == 4){
        float4 b4 = *(const float4*)&Wt[k*OUT + tx*4];
        bv[0]=b4.x; bv[1]=b4.y; bv[2]=b4.z; bv[3]=b4.w;
      } else if constexpr (CPT == 2){
        float2 b2 = *(const float2*)&Wt[k*OUT + tx*2];
        bv[0]=b2.x; bv[1]=b2.y;
      } else {
        bv[0] = Wt[k*OUT + tx];
      }
#pragma unroll
      for (int i=0;i<8;i++)
#pragma unroll
        for (int j=0;j<CPT;j++)
          acc[i][j] = fmaf(ar[i], bv[j], acc[i][j]);
    }
    __syncthreads();
  }

  if constexpr (!DOTEP){
#pragma unroll
    for (int i=0;i<8;i++){
      int gr = base + ty*8 + i;
      if (gr < nrows){
        float rs = 1.f;
        if constexpr (SCALE) rs = rr[gr];
        float v[CPT];
#pragma unroll
        for (int j=0;j<CPT;j++){
          float x = acc[i][j];
          if constexpr (BIAS) x += bias[tx*CPT + j];
          if constexpr (RELU) x = fmaxf(x, 0.f);
          if constexpr (SCALE) x *= rs;
          v[j] = x;
        }
        if constexpr (CBF){
          u16* Cb = (u16*)Cp;
          if constexpr (CPT == 4){
            ushort4 o; o.x=f2b(v[0]); o.y=f2b(v[1]); o.z=f2b(v[2]); o.w=f2b(v[3]);
            *(ushort4*)(Cb + (size_t)gr*OUT + tx*4) = o;
          } else if constexpr (CPT == 2){
            ushort2 o; o.x=f2b(v[0]); o.y=f2b(v[1]);
            *(ushort2*)(Cb + (size_t)gr*OUT + tx*2) = o;
          } else {
            Cb[(size_t)gr*OUT + tx] = f2b(v[0]);
          }
        } else {
          float* Cf = (float*)Cp;
#pragma unroll
          for (int j=0;j<CPT;j++) Cf[(size_t)gr*OUT + tx*CPT + j] = v[j];
        }
      }
    }
  } else {
    float p3 = P3[tx];
    float pb = pb3[0];
    float bb = bias[tx];
#pragma unroll
    for (int i=0;i<8;i++){
      float v = fmaxf(acc[i][0] + bb, 0.f);
      float part = v * p3;
      part += __shfl_xor(part, 16);
      part += __shfl_xor(part, 8);
      part += __shfl_xor(part, 4);
      part += __shfl_xor(part, 2);
      part += __shfl_xor(part, 1);
      int gr = base + ty*8 + i;
      if (tx == 0 && gr < nrows){
        outp[gr] = 1.f / (1.f + __expf(-(part + pb)));
      }
    }
  }
}

// ---------------- launcher ----------------

extern "C" void kernel_launch(void* const* d_in, const int* in_sizes, int n_in,
                              void* d_out, int out_size, void* d_ws, size_t ws_size,
                              hipStream_t stream){
  const float* ut  = (const float*)d_in[0];
  const float* it  = (const float*)d_in[1];
  const float* W1  = (const float*)d_in[2];
  const float* b1  = (const float*)d_in[3];
  const float* W2  = (const float*)d_in[4];
  const float* b2  = (const float*)d_in[5];
  const float* W3  = (const float*)d_in[6];
  const float* b3  = (const float*)d_in[7];
  const float* P1  = (const float*)d_in[8];
  const float* pb1 = (const float*)d_in[9];
  const float* P2  = (const float*)d_in[10];
  const float* pb2 = (const float*)d_in[11];
  const float* P3  = (const float*)d_in[12];
  const float* pb3 = (const float*)d_in[13];
  const int* src  = (const int*)d_in[14];
  const int* dst  = (const int*)d_in[15];
  const int* uidx = (const int*)d_in[16];
  const int* vidx = (const int*)d_in[17];

  const int NU = in_sizes[0] / 64;
  const int NI = in_sizes[1] / 64;
  const int N  = NU + NI;
  const int NE = in_sizes[14];
  const int B  = in_sizes[16];
  const int K  = (N + 255) >> 8;         // buckets of 256 nodes

  char* w = (char*)d_ws;
  auto alloc = [&](size_t bytes)->void*{
    void* p = (void*)w;
    w += (bytes + 255) & ~(size_t)255;
    return p;
  };
  float* r       = (float*)alloc((size_t)N*4);
  int*   row_ptr = (int*)  alloc((size_t)(N+1)*4);
  u32*   bhist   = (u32*)  alloc((size_t)K*4);
  u32*   bbase   = (u32*)  alloc((size_t)(K+1)*4);
  u32*   gcur    = (u32*)  alloc((size_t)K*4);
  int*   col     = (int*)  alloc((size_t)NE*4);
  float* bufA    = (float*)alloc((size_t)N*128*4);   // ebuf (pre) -> m2 (f32) -> A1
  float* bufB    = (float*)alloc((size_t)N*64*4);    // m1 (f32) -> x3 (f32)
  u16*   bufC    = (u16*)  alloc((size_t)N*128*2);   // h1 (bf16) -> h2 (bf16)
  u16*   bufD    = (u16*)  alloc((size_t)N*64*2);    // x0 (bf16) -> g3 (bf16)
  if ((size_t)(w - (char*)d_ws) > ws_size) return;

  u32* ebuf = (u32*)bufA;  // dead before k_agg128 writes m2

  hipMemsetAsync(bhist, 0, (size_t)K*4, stream);

  int g;
  k_histK  <<<128, 256, (size_t)K*4, stream>>>(dst, NE, K, bhist);
  k_scanK  <<<1, 256, 0, stream>>>(bhist, K, bbase, gcur);
  g = (NE + 4095)/4096;
  k_scatterR<<<g, 256, (size_t)K*4, stream>>>(src, dst, NE, K, gcur, ebuf);
  k_csr    <<<K, 256, 0, stream>>>(ebuf, bbase, N, NE, row_ptr, r, col);

  const int ga = (N + 3)/4;     // 4 waves (nodes) per block
  const int gb = (N + 63)/64;
  const int gm = (B + 63)/64;

  u16* x0 = bufD;
  g = (N*64/4 + 255)/256; k_scale0<<<g,256,0,stream>>>(ut, it, r, x0, N, NU);

  float* m1 = bufB;
  k_agg1<<<ga,256,0,stream>>>(x0, r, row_ptr, col, m1, N);
  u16* h1 = bufC;
  k_gemm<64,128,true,true,true,false,false,false,true><<<gb,256,0,stream>>>(
      m1, W1, b1, r, h1, N, NU, nullptr, nullptr, nullptr, nullptr, nullptr);

  float* m2 = bufA;               // ebuf dead from here
  k_agg128<<<ga,256,0,stream>>>(h1, r, row_ptr, col, m2, N);
  u16* h2 = bufC;
  k_gemm<128,128,true,true,true,false,false,false,true><<<gb,256,0,stream>>>(
      m2, W2, b2, r, h2, N, NU, nullptr, nullptr, nullptr, nullptr, nullptr);

  u16* g3 = bufD;
  k_gemm<128,64,false,false,false,false,false,true,true><<<gb,256,0,stream>>>(
      h2, W3, nullptr, nullptr, g3, N, NU, nullptr, nullptr, nullptr, nullptr, nullptr);

  float* x3 = bufB;
  k_agg64b<<<ga,256,0,stream>>>(g3, r, row_ptr, col, b3, x3, N);

  float* A1 = bufA;
  k_gemm<128,64,true,true,false,true,false,false,false><<<gm,256,0,stream>>>(
      x3, P1, pb1, nullptr, A1, B, NU, uidx, vidx, nullptr, nullptr, nullptr);

  k_gemm<64,32,true,true,false,false,true,false,false><<<gm,256,0,stream>>>(
      A1, P2, pb2, nullptr, nullptr, B, NU, nullptr, nullptr, P3, pb3, (float*)d_out);
}

// Round 6
// 705.170 us; speedup vs baseline: 1.7502x; 1.2568x over previous
//
#include <hip/hip_runtime.h>
#include <hip/hip_bf16.h>

// f32 in/out. ALL gather-fed and GEMM-A intermediates (x0,m1,h1,m2,h2,g3,x3)
// stored bf16, f32 accumulation. Agg kernels: G-lane edge groups (G=D/8),
// uint4 loads (16B/lane), 4-8 independent gather chains per wave (round-5
// counters showed latency-bound: VALU 24%, HBM 29%, neither saturated).
// CSR build: block-aggregated reservation scatter (round-5 proven).

typedef unsigned short u16;
typedef unsigned int   u32;

__device__ __forceinline__ float b2f(u16 u){
  union { u32 i; float f; } c; c.i = ((u32)u) << 16; return c.f;
}
__device__ __forceinline__ u16 f2b(float f){
  union { float f; u32 i; } c; c.f = f;
  u32 x = c.i;
  u32 r = x + 0x7FFFu + ((x >> 16) & 1u);   // round-to-nearest-even
  return (u16)(r >> 16);
}

// ---------------- graph preprocessing: aggregated bucket scatter ----------------
// bucket b = dst >> 8 (256 nodes), K = ceil(N/256). packed edge = (dst&255)<<18 | src.

__global__ __launch_bounds__(256) void k_histK(const int* __restrict__ dst, int ne, int K,
                                               u32* __restrict__ bhist){
  extern __shared__ u32 sh[];
  int t = threadIdx.x;
  for (int i = t; i < K; i += 256) sh[i] = 0;
  __syncthreads();
  for (int i = blockIdx.x*256 + t; i < ne; i += gridDim.x*256)
    atomicAdd(&sh[dst[i] >> 8], 1u);
  __syncthreads();
  int rot = (int)((blockIdx.x * 73u) % (u32)K);
  for (int jj = t; jj < K; jj += 256){
    int i = jj + rot; if (i >= K) i -= K;
    u32 v = sh[i];
    if (v) atomicAdd(&bhist[i], v);
  }
}

__global__ __launch_bounds__(256) void k_scanK(const u32* __restrict__ bhist, int K,
                                               u32* __restrict__ bbase, u32* __restrict__ gcur){
  __shared__ u32 s[256];
  int t = threadIdx.x;
  int items = (K + 255) / 256;
  u32 local[16];
  int s0 = t * items;
  u32 sum = 0;
  for (int j = 0; j < items; j++){
    int idx = s0 + j;
    u32 v = (idx < K) ? bhist[idx] : 0;
    local[j] = v; sum += v;
  }
  s[t] = sum; __syncthreads();
  for (int off = 1; off < 256; off <<= 1){
    u32 add = (t >= off) ? s[t-off] : 0;
    __syncthreads();
    s[t] += add;
    __syncthreads();
  }
  u32 run = s[t] - sum;
  for (int j = 0; j < items; j++){
    int idx = s0 + j;
    if (idx < K){ bbase[idx] = run; gcur[idx] = run; }
    run += local[j];
  }
  if (t == 255) bbase[K] = s[255];
}

__global__ __launch_bounds__(256) void k_scatterR(const int* __restrict__ src, const int* __restrict__ dst,
                                                  int ne, int K, u32* __restrict__ gcur,
                                                  u32* __restrict__ ebuf){
  extern __shared__ u32 cnt[];
  int t = threadIdx.x;
  int e0 = blockIdx.x * 4096;
  for (int i = t; i < K; i += 256) cnt[i] = 0;
  __syncthreads();
#pragma unroll
  for (int j = 0; j < 16; j++){
    int e = e0 + j*256 + t;
    if (e < ne) atomicAdd(&cnt[dst[e] >> 8], 1u);
  }
  __syncthreads();
  int rot = (int)((blockIdx.x * 73u) % (u32)K);
  for (int jj = t; jj < K; jj += 256){
    int i = jj + rot; if (i >= K) i -= K;
    u32 c = cnt[i];
    if (c) cnt[i] = atomicAdd(&gcur[i], c);
  }
  __syncthreads();
#pragma unroll
  for (int j = 0; j < 16; j++){
    int e = e0 + j*256 + t;
    if (e < ne){
      int d = dst[e];
      u32 p = atomicAdd(&cnt[d >> 8], 1u);
      ebuf[p] = ((u32)(d & 255) << 18) | (u32)src[e];
    }
  }
}

__global__ __launch_bounds__(256) void k_csr(const u32* __restrict__ ebuf, const u32* __restrict__ bbase,
                                             int n, int ne, int* __restrict__ row_ptr,
                                             float* __restrict__ r, int* __restrict__ col){
  __shared__ u32 cnt[256];
  __shared__ u32 pfx[256];
  __shared__ u32 cur[256];
  int b = blockIdx.x, t = threadIdx.x;
  u32 bb = bbase[b], be = bbase[b+1];
  int nbase = b << 8;
  int nn = n - nbase; if (nn > 256) nn = 256;
  cnt[t] = 0;
  __syncthreads();
  for (u32 e = bb + t; e < be; e += 256)
    atomicAdd(&cnt[ebuf[e] >> 18], 1u);
  __syncthreads();
  pfx[t] = cnt[t];
  __syncthreads();
  for (int off = 1; off < 256; off <<= 1){
    u32 add = (t >= off) ? pfx[t-off] : 0;
    __syncthreads();
    pfx[t] += add;
    __syncthreads();
  }
  u32 excl = pfx[t] - cnt[t];
  cur[t] = bb + excl;
  if (t < nn){
    row_ptr[nbase + t] = (int)(bb + excl);
    r[nbase + t] = rsqrtf(fmaxf((float)cnt[t], 1.0f));
  }
  __syncthreads();
  for (u32 e = bb + t; e < be; e += 256){
    u32 v = ebuf[e];
    u32 p = atomicAdd(&cur[v >> 18], 1u);
    col[p] = (int)(v & 0x3FFFFu);
  }
  if (b == 0 && t == 0) row_ptr[n] = ne;
}

// x0[n,64] (bf16) = concat(ut,it)[n,:] * r[n]
__global__ __launch_bounds__(256) void k_scale0(const float* __restrict__ ut, const float* __restrict__ it,
    const float* __restrict__ r, u16* __restrict__ x0, int n, int nu){
  int i = blockIdx.x*256 + threadIdx.x;
  int base = i*4;
  if (base < n*64){
    int node = base >> 6;
    float rv = r[node];
    const float* srcp = (node < nu) ? (ut + (size_t)node*64) : (it + (size_t)(node-nu)*64);
    float4 v = *(const float4*)(srcp + (base & 63));
    ushort4 o;
    o.x = f2b(v.x*rv); o.y = f2b(v.y*rv); o.z = f2b(v.z*rv); o.w = f2b(v.w*rv);
    *(ushort4*)(x0 + base) = o;
  }
}

// ---------------- aggregation: one wave per node, G-lane edge groups ----------------
// G = D/8 lanes cooperate on one edge (uint4 = 8 bf16 dims per lane).
// E = 64/G edges in flight per wave. Cross-group combine via shfl_xor.
// out[wid] (bf16) = r[wid] * sum_s in[s]  (+ bias if BIAS).
template<int D, bool BIAS>
__global__ __launch_bounds__(256) void k_agg(const u16* __restrict__ x, const float* __restrict__ r,
    const int* __restrict__ row_ptr, const int* __restrict__ col,
    const float* __restrict__ bias, u16* __restrict__ out, int n){
  constexpr int G = D/8;
  constexpr int E = 64/G;
  int wid = (blockIdx.x*256 + threadIdx.x) >> 6;
  int lane = threadIdx.x & 63;
  if (wid >= n) return;
  int gidx = lane / G;
  int l    = lane % G;          // covers dims l*8 .. l*8+7
  int beg = row_ptr[wid], end = row_ptr[wid+1];
  float a[8] = {0.f,0.f,0.f,0.f,0.f,0.f,0.f,0.f};
  for (int e = beg + gidx; e < end; e += E){
    int s = col[e];
    uint4 u = *(const uint4*)(x + (size_t)s*D + l*8);
    a[0] += b2f((u16)(u.x & 0xffff)); a[1] += b2f((u16)(u.x >> 16));
    a[2] += b2f((u16)(u.y & 0xffff)); a[3] += b2f((u16)(u.y >> 16));
    a[4] += b2f((u16)(u.z & 0xffff)); a[5] += b2f((u16)(u.z >> 16));
    a[6] += b2f((u16)(u.w & 0xffff)); a[7] += b2f((u16)(u.w >> 16));
  }
#pragma unroll
  for (int off = G; off < 64; off <<= 1){
#pragma unroll
    for (int i = 0; i < 8; i++) a[i] += __shfl_xor(a[i], off);
  }
  if (gidx == 0){
    float rn = r[wid];
    float v[8];
#pragma unroll
    for (int i = 0; i < 8; i++){
      float y = a[i] * rn;
      if constexpr (BIAS) y += bias[l*8 + i];
      v[i] = y;
    }
    uint4 o;
    o.x = (u32)f2b(v[0]) | ((u32)f2b(v[1]) << 16);
    o.y = (u32)f2b(v[2]) | ((u32)f2b(v[3]) << 16);
    o.z = (u32)f2b(v[4]) | ((u32)f2b(v[5]) << 16);
    o.w = (u32)f2b(v[6]) | ((u32)f2b(v[7]) << 16);
    *(uint4*)(out + (size_t)wid*D + l*8) = o;
  }
}

// ---------------- tiled f32-math GEMM: C = act(A @ W + b) * r ----------------
// ABF: A bf16. CBF: C bf16. GATHER: A rows from idx (works with ABF; row=64).
// DOTEP: OUT=32, fused P3-dot + sigmoid.
template<int IN, int OUT, bool BIAS, bool RELU, bool SCALE, bool GATHER, bool DOTEP,
         bool ABF, bool CBF>
__global__ __launch_bounds__(256) void k_gemm(
    const void* __restrict__ Ap, const float* __restrict__ W, const float* __restrict__ bias,
    const float* __restrict__ rr, void* __restrict__ Cp, int nrows, int nu,
    const int* __restrict__ uidx, const int* __restrict__ vidx,
    const float* __restrict__ P3, const float* __restrict__ pb3, float* __restrict__ outp)
{
  constexpr int CPT = OUT/32;
  __shared__ float At[64][68];
  __shared__ float Wt[64*OUT];
  const int t  = threadIdx.x;
  const int tx = t & 31, ty = t >> 5;
  const int base = blockIdx.x * 64;

  float acc[8][CPT];
#pragma unroll
  for (int i=0;i<8;i++)
#pragma unroll
    for (int j=0;j<CPT;j++) acc[i][j] = 0.f;

  for (int kt = 0; kt < IN; kt += 64){
#pragma unroll
    for (int q=0;q<4;q++){
      int f = t + 256*q;
      int row = f >> 4;
      int k4  = (f & 15) << 2;
      int gr  = base + row;
      float4 a = make_float4(0.f,0.f,0.f,0.f);
      if (gr < nrows){
        if constexpr (ABF){
          const u16* Ab = (const u16*)Ap;
          const u16* ap;
          if constexpr (GATHER){
            int node = (kt == 0) ? uidx[gr] : (nu + vidx[gr]);
            ap = Ab + (size_t)node*64 + k4;
          } else {
            ap = Ab + (size_t)gr*IN + kt + k4;
          }
          ushort4 v = *(const ushort4*)ap;
          a = make_float4(b2f(v.x), b2f(v.y), b2f(v.z), b2f(v.w));
        } else {
          const float* Af = (const float*)Ap;
          const float* ap;
          if constexpr (GATHER){
            int node = (kt == 0) ? uidx[gr] : (nu + vidx[gr]);
            ap = Af + (size_t)node*64 + k4;
          } else {
            ap = Af + (size_t)gr*IN + kt + k4;
          }
          a = *(const float4*)ap;
        }
      }
      At[k4+0][row] = a.x; At[k4+1][row] = a.y; At[k4+2][row] = a.z; At[k4+3][row] = a.w;
    }
    for (int f = t; f < 64*OUT; f += 256){
      Wt[f] = W[(size_t)kt*OUT + f];
    }
    __syncthreads();

#pragma unroll 16
    for (int k=0;k<64;k++){
      const float4 a0 = *(const float4*)&At[k][ty*8];
      const float4 a1 = *(const float4*)&At[k][ty*8+4];
      float ar[8] = {a0.x,a0.y,a0.z,a0.w,a1.x,a1.y,a1.z,a1.w};
      float bv[CPT];
      if constexpr (CPT == 4){
        float4 b4 = *(const float4*)&Wt[k*OUT + tx*4];
        bv[0]=b4.x; bv[1]=b4.y; bv[2]=b4.z; bv[3]=b4.w;
      } else if constexpr (CPT == 2){
        float2 b2 = *(const float2*)&Wt[k*OUT + tx*2];
        bv[0]=b2.x; bv[1]=b2.y;
      } else {
        bv[0] = Wt[k*OUT + tx];
      }
#pragma unroll
      for (int i=0;i<8;i++)
#pragma unroll
        for (int j=0;j<CPT;j++)
          acc[i][j] = fmaf(ar[i], bv[j], acc[i][j]);
    }
    __syncthreads();
  }

  if constexpr (!DOTEP){
#pragma unroll
    for (int i=0;i<8;i++){
      int gr = base + ty*8 + i;
      if (gr < nrows){
        float rs = 1.f;
        if constexpr (SCALE) rs = rr[gr];
        float v[CPT];
#pragma unroll
        for (int j=0;j<CPT;j++){
          float x = acc[i][j];
          if constexpr (BIAS) x += bias[tx*CPT + j];
          if constexpr (RELU) x = fmaxf(x, 0.f);
          if constexpr (SCALE) x *= rs;
          v[j] = x;
        }
        if constexpr (CBF){
          u16* Cb = (u16*)Cp;
          if constexpr (CPT == 4){
            ushort4 o; o.x=f2b(v[0]); o.y=f2b(v[1]); o.z=f2b(v[2]); o.w=f2b(v[3]);
            *(ushort4*)(Cb + (size_t)gr*OUT + tx*4) = o;
          } else if constexpr (CPT == 2){
            ushort2 o; o.x=f2b(v[0]); o.y=f2b(v[1]);
            *(ushort2*)(Cb + (size_t)gr*OUT + tx*2) = o;
          } else {
            Cb[(size_t)gr*OUT + tx] = f2b(v[0]);
          }
        } else {
          float* Cf = (float*)Cp;
#pragma unroll
          for (int j=0;j<CPT;j++) Cf[(size_t)gr*OUT + tx*CPT + j] = v[j];
        }
      }
    }
  } else {
    float p3 = P3[tx];
    float pb = pb3[0];
    float bb = bias[tx];
#pragma unroll
    for (int i=0;i<8;i++){
      float v = fmaxf(acc[i][0] + bb, 0.f);
      float part = v * p3;
      part += __shfl_xor(part, 16);
      part += __shfl_xor(part, 8);
      part += __shfl_xor(part, 4);
      part += __shfl_xor(part, 2);
      part += __shfl_xor(part, 1);
      int gr = base + ty*8 + i;
      if (tx == 0 && gr < nrows){
        outp[gr] = 1.f / (1.f + __expf(-(part + pb)));
      }
    }
  }
}

// ---------------- launcher ----------------

extern "C" void kernel_launch(void* const* d_in, const int* in_sizes, int n_in,
                              void* d_out, int out_size, void* d_ws, size_t ws_size,
                              hipStream_t stream){
  const float* ut  = (const float*)d_in[0];
  const float* it  = (const float*)d_in[1];
  const float* W1  = (const float*)d_in[2];
  const float* b1  = (const float*)d_in[3];
  const float* W2  = (const float*)d_in[4];
  const float* b2  = (const float*)d_in[5];
  const float* W3  = (const float*)d_in[6];
  const float* b3  = (const float*)d_in[7];
  const float* P1  = (const float*)d_in[8];
  const float* pb1 = (const float*)d_in[9];
  const float* P2  = (const float*)d_in[10];
  const float* pb2 = (const float*)d_in[11];
  const float* P3  = (const float*)d_in[12];
  const float* pb3 = (const float*)d_in[13];
  const int* src  = (const int*)d_in[14];
  const int* dst  = (const int*)d_in[15];
  const int* uidx = (const int*)d_in[16];
  const int* vidx = (const int*)d_in[17];

  const int NU = in_sizes[0] / 64;
  const int NI = in_sizes[1] / 64;
  const int N  = NU + NI;
  const int NE = in_sizes[14];
  const int B  = in_sizes[16];
  const int K  = (N + 255) >> 8;

  char* w = (char*)d_ws;
  auto alloc = [&](size_t bytes)->void*{
    void* p = (void*)w;
    w += (bytes + 255) & ~(size_t)255;
    return p;
  };
  float* r       = (float*)alloc((size_t)N*4);
  int*   row_ptr = (int*)  alloc((size_t)(N+1)*4);
  u32*   bhist   = (u32*)  alloc((size_t)K*4);
  u32*   bbase   = (u32*)  alloc((size_t)(K+1)*4);
  u32*   gcur    = (u32*)  alloc((size_t)K*4);
  int*   col     = (int*)  alloc((size_t)NE*4);
  char*  bufE    = (char*) alloc((size_t)N*64*2 > (size_t)NE*4 ? (size_t)N*64*2 : (size_t)NE*4);
                                                      // ebuf(u32,NE) -> m1(bf16) -> x3(bf16)
  char*  bufF    = (char*) alloc((size_t)N*128*2 > (size_t)B*64*4 ? (size_t)N*128*2 : (size_t)B*64*4);
                                                      // m2(bf16) -> A1(f32,B*64)
  u16*   bufC    = (u16*)  alloc((size_t)N*128*2);    // h1 -> h2
  u16*   bufD    = (u16*)  alloc((size_t)N*64*2);     // x0 -> g3
  if ((size_t)(w - (char*)d_ws) > ws_size) return;

  u32* ebuf = (u32*)bufE;

  hipMemsetAsync(bhist, 0, (size_t)K*4, stream);

  int g;
  k_histK  <<<128, 256, (size_t)K*4, stream>>>(dst, NE, K, bhist);
  k_scanK  <<<1, 256, 0, stream>>>(bhist, K, bbase, gcur);
  g = (NE + 4095)/4096;
  k_scatterR<<<g, 256, (size_t)K*4, stream>>>(src, dst, NE, K, gcur, ebuf);
  k_csr    <<<K, 256, 0, stream>>>(ebuf, bbase, N, NE, row_ptr, r, col);

  const int ga = (N + 3)/4;
  const int gb = (N + 63)/64;
  const int gm = (B + 63)/64;

  u16* x0 = bufD;
  g = (N*64/4 + 255)/256; k_scale0<<<g,256,0,stream>>>(ut, it, r, x0, N, NU);

  u16* m1 = (u16*)bufE;               // ebuf dead after k_csr
  k_agg<64,false><<<ga,256,0,stream>>>(x0, r, row_ptr, col, nullptr, m1, N);
  u16* h1 = bufC;
  k_gemm<64,128,true,true,true,false,false,true,true><<<gb,256,0,stream>>>(
      m1, W1, b1, r, h1, N, NU, nullptr, nullptr, nullptr, nullptr, nullptr);

  u16* m2 = (u16*)bufF;
  k_agg<128,false><<<ga,256,0,stream>>>(h1, r, row_ptr, col, nullptr, m2, N);
  u16* h2 = bufC;                     // h1 dead after agg
  k_gemm<128,128,true,true,true,false,false,true,true><<<gb,256,0,stream>>>(
      m2, W2, b2, r, h2, N, NU, nullptr, nullptr, nullptr, nullptr, nullptr);

  u16* g3 = bufD;                     // x0 dead after first agg
  k_gemm<128,64,false,false,false,false,false,true,true><<<gb,256,0,stream>>>(
      h2, W3, nullptr, nullptr, g3, N, NU, nullptr, nullptr, nullptr, nullptr, nullptr);

  u16* x3 = (u16*)bufE;               // m1 dead after GEMM1
  k_agg<64,true><<<ga,256,0,stream>>>(g3, r, row_ptr, col, b3, x3, N);

  float* A1 = (float*)bufF;           // m2 dead after GEMM2
  k_gemm<128,64,true,true,false,true,false,true,false><<<gm,256,0,stream>>>(
      x3, P1, pb1, nullptr, A1, B, NU, uidx, vidx, nullptr, nullptr, nullptr);

  k_gemm<64,32,true,true,false,false,true,false,false><<<gm,256,0,stream>>>(
      A1, P2, pb2, nullptr, nullptr, B, NU, nullptr, nullptr, P3, pb3, (float*)d_out);
}

// Round 7
// 500.865 us; speedup vs baseline: 2.4641x; 1.4079x over previous
//
#include <hip/hip_runtime.h>
#include <hip/hip_bf16.h>

// f32 in/out. All intermediates bf16 (f32 accumulation). GEMMs now MFMA
// 16x16x32_bf16: round-6 counters showed vector GEMM at VALU 45% / Mfma 0 /
// occupancy 19% (50KB LDS) / 4.2M LDS conflicts. MFMA layout (m89-verified):
// A[m=lane&15][k=quad*8+j], B[k=quad*8+j][n=lane&15], D[row=quad*4+reg][col=lane&15].
// CSR build: block-aggregated reservation scatter (round-5 proven).

typedef unsigned short u16;
typedef unsigned int   u32;
typedef __attribute__((ext_vector_type(8))) short short8;
typedef __attribute__((ext_vector_type(4))) float f32x4;

__device__ __forceinline__ float b2f(u16 u){
  union { u32 i; float f; } c; c.i = ((u32)u) << 16; return c.f;
}
__device__ __forceinline__ u16 f2b(float f){
  union { float f; u32 i; } c; c.f = f;
  u32 x = c.i;
  u32 r = x + 0x7FFFu + ((x >> 16) & 1u);   // round-to-nearest-even
  return (u16)(r >> 16);
}

// ---------------- graph preprocessing: aggregated bucket scatter ----------------

__global__ __launch_bounds__(256) void k_histK(const int* __restrict__ dst, int ne, int K,
                                               u32* __restrict__ bhist){
  extern __shared__ u32 sh[];
  int t = threadIdx.x;
  for (int i = t; i < K; i += 256) sh[i] = 0;
  __syncthreads();
  for (int i = blockIdx.x*256 + t; i < ne; i += gridDim.x*256)
    atomicAdd(&sh[dst[i] >> 8], 1u);
  __syncthreads();
  int rot = (int)((blockIdx.x * 73u) % (u32)K);
  for (int jj = t; jj < K; jj += 256){
    int i = jj + rot; if (i >= K) i -= K;
    u32 v = sh[i];
    if (v) atomicAdd(&bhist[i], v);
  }
}

__global__ __launch_bounds__(256) void k_scanK(const u32* __restrict__ bhist, int K,
                                               u32* __restrict__ bbase, u32* __restrict__ gcur){
  __shared__ u32 s[256];
  int t = threadIdx.x;
  int items = (K + 255) / 256;
  u32 local[16];
  int s0 = t * items;
  u32 sum = 0;
  for (int j = 0; j < items; j++){
    int idx = s0 + j;
    u32 v = (idx < K) ? bhist[idx] : 0;
    local[j] = v; sum += v;
  }
  s[t] = sum; __syncthreads();
  for (int off = 1; off < 256; off <<= 1){
    u32 add = (t >= off) ? s[t-off] : 0;
    __syncthreads();
    s[t] += add;
    __syncthreads();
  }
  u32 run = s[t] - sum;
  for (int j = 0; j < items; j++){
    int idx = s0 + j;
    if (idx < K){ bbase[idx] = run; gcur[idx] = run; }
    run += local[j];
  }
  if (t == 255) bbase[K] = s[255];
}

__global__ __launch_bounds__(256) void k_scatterR(const int* __restrict__ src, const int* __restrict__ dst,
                                                  int ne, int K, u32* __restrict__ gcur,
                                                  u32* __restrict__ ebuf){
  extern __shared__ u32 cnt[];
  int t = threadIdx.x;
  int e0 = blockIdx.x * 4096;
  for (int i = t; i < K; i += 256) cnt[i] = 0;
  __syncthreads();
#pragma unroll
  for (int j = 0; j < 16; j++){
    int e = e0 + j*256 + t;
    if (e < ne) atomicAdd(&cnt[dst[e] >> 8], 1u);
  }
  __syncthreads();
  int rot = (int)((blockIdx.x * 73u) % (u32)K);
  for (int jj = t; jj < K; jj += 256){
    int i = jj + rot; if (i >= K) i -= K;
    u32 c = cnt[i];
    if (c) cnt[i] = atomicAdd(&gcur[i], c);
  }
  __syncthreads();
#pragma unroll
  for (int j = 0; j < 16; j++){
    int e = e0 + j*256 + t;
    if (e < ne){
      int d = dst[e];
      u32 p = atomicAdd(&cnt[d >> 8], 1u);
      ebuf[p] = ((u32)(d & 255) << 18) | (u32)src[e];
    }
  }
}

__global__ __launch_bounds__(256) void k_csr(const u32* __restrict__ ebuf, const u32* __restrict__ bbase,
                                             int n, int ne, int* __restrict__ row_ptr,
                                             float* __restrict__ r, int* __restrict__ col){
  __shared__ u32 cnt[256];
  __shared__ u32 pfx[256];
  __shared__ u32 cur[256];
  int b = blockIdx.x, t = threadIdx.x;
  u32 bb = bbase[b], be = bbase[b+1];
  int nbase = b << 8;
  int nn = n - nbase; if (nn > 256) nn = 256;
  cnt[t] = 0;
  __syncthreads();
  for (u32 e = bb + t; e < be; e += 256)
    atomicAdd(&cnt[ebuf[e] >> 18], 1u);
  __syncthreads();
  pfx[t] = cnt[t];
  __syncthreads();
  for (int off = 1; off < 256; off <<= 1){
    u32 add = (t >= off) ? pfx[t-off] : 0;
    __syncthreads();
    pfx[t] += add;
    __syncthreads();
  }
  u32 excl = pfx[t] - cnt[t];
  cur[t] = bb + excl;
  if (t < nn){
    row_ptr[nbase + t] = (int)(bb + excl);
    r[nbase + t] = rsqrtf(fmaxf((float)cnt[t], 1.0f));
  }
  __syncthreads();
  for (u32 e = bb + t; e < be; e += 256){
    u32 v = ebuf[e];
    u32 p = atomicAdd(&cur[v >> 18], 1u);
    col[p] = (int)(v & 0x3FFFFu);
  }
  if (b == 0 && t == 0) row_ptr[n] = ne;
}

// convert the 5 weight matrices f32 -> bf16 into one concatenated buffer
__global__ __launch_bounds__(256) void k_cvtW(const float* __restrict__ a0, const float* __restrict__ a1,
    const float* __restrict__ a2, const float* __restrict__ a3, const float* __restrict__ a4,
    int n0, int n1, int n2, int n3, int n4, u16* __restrict__ out){
  int i = blockIdx.x*256 + threadIdx.x;
  int idx = i;
  const float* s;
  if (idx < n0){ s = a0; }
  else { idx -= n0;
    if (idx < n1){ s = a1; }
    else { idx -= n1;
      if (idx < n2){ s = a2; }
      else { idx -= n2;
        if (idx < n3){ s = a3; }
        else { idx -= n3;
          if (idx >= n4) return;
          s = a4;
        }
      }
    }
  }
  out[i] = f2b(s[idx]);
}

// x0[n,64] (bf16) = concat(ut,it)[n,:] * r[n]
__global__ __launch_bounds__(256) void k_scale0(const float* __restrict__ ut, const float* __restrict__ it,
    const float* __restrict__ r, u16* __restrict__ x0, int n, int nu){
  int i = blockIdx.x*256 + threadIdx.x;
  int base = i*4;
  if (base < n*64){
    int node = base >> 6;
    float rv = r[node];
    const float* srcp = (node < nu) ? (ut + (size_t)node*64) : (it + (size_t)(node-nu)*64);
    float4 v = *(const float4*)(srcp + (base & 63));
    ushort4 o;
    o.x = f2b(v.x*rv); o.y = f2b(v.y*rv); o.z = f2b(v.z*rv); o.w = f2b(v.w*rv);
    *(ushort4*)(x0 + base) = o;
  }
}

// ---------------- aggregation: one wave per node, G-lane edge groups ----------------
template<int D, bool BIAS>
__global__ __launch_bounds__(256) void k_agg(const u16* __restrict__ x, const float* __restrict__ r,
    const int* __restrict__ row_ptr, const int* __restrict__ col,
    const float* __restrict__ bias, u16* __restrict__ out, int n){
  constexpr int G = D/8;
  constexpr int E = 64/G;
  int wid = (blockIdx.x*256 + threadIdx.x) >> 6;
  int lane = threadIdx.x & 63;
  if (wid >= n) return;
  int gidx = lane / G;
  int l    = lane % G;
  int beg = row_ptr[wid], end = row_ptr[wid+1];
  float a[8] = {0.f,0.f,0.f,0.f,0.f,0.f,0.f,0.f};
  for (int e = beg + gidx; e < end; e += E){
    int s = col[e];
    uint4 u = *(const uint4*)(x + (size_t)s*D + l*8);
    a[0] += b2f((u16)(u.x & 0xffff)); a[1] += b2f((u16)(u.x >> 16));
    a[2] += b2f((u16)(u.y & 0xffff)); a[3] += b2f((u16)(u.y >> 16));
    a[4] += b2f((u16)(u.z & 0xffff)); a[5] += b2f((u16)(u.z >> 16));
    a[6] += b2f((u16)(u.w & 0xffff)); a[7] += b2f((u16)(u.w >> 16));
  }
#pragma unroll
  for (int off = G; off < 64; off <<= 1){
#pragma unroll
    for (int i = 0; i < 8; i++) a[i] += __shfl_xor(a[i], off);
  }
  if (gidx == 0){
    float rn = r[wid];
    float v[8];
#pragma unroll
    for (int i = 0; i < 8; i++){
      float y = a[i] * rn;
      if constexpr (BIAS) y += bias[l*8 + i];
      v[i] = y;
    }
    uint4 o;
    o.x = (u32)f2b(v[0]) | ((u32)f2b(v[1]) << 16);
    o.y = (u32)f2b(v[2]) | ((u32)f2b(v[3]) << 16);
    o.z = (u32)f2b(v[4]) | ((u32)f2b(v[5]) << 16);
    o.w = (u32)f2b(v[6]) | ((u32)f2b(v[7]) << 16);
    *(uint4*)(out + (size_t)wid*D + l*8) = o;
  }
}

// ---------------- MFMA GEMM: C[nrows,OUT] = act(A[nrows,K_] @ W + b) * r ----------------
// 256 thr = 4 waves; wave covers 32 rows (2 m-tiles), block 128 rows.
// A bf16 row-major, direct global->VGPR frags. W bf16 [K_,OUT], staged W^T in
// LDS (pad +8). GATHER: row k<64 from A[uidx]*64, k>=64 from A[(nu+vidx)]*64.
// DOTEP: OUT=32, relu -> dot P3 -> sigmoid -> f32 out.
template<int K_, int OUT, bool BIAS, bool RELU, bool SCALE, bool GATHER, bool DOTEP>
__global__ __launch_bounds__(256) void k_mgemm(
    const u16* __restrict__ A, const u16* __restrict__ Wb, const float* __restrict__ bias,
    const float* __restrict__ rr, u16* __restrict__ C, int nrows, int nu,
    const int* __restrict__ uidx, const int* __restrict__ vidx,
    const float* __restrict__ P3, const float* __restrict__ pb3, float* __restrict__ outp)
{
  constexpr int KP = K_ + 8;
  constexpr int NT = OUT / 16;
  constexpr int KS = K_ / 32;
  __shared__ u16 Wt[OUT * KP];
  const int t = threadIdx.x;

  for (int i = t; i < (K_*OUT)/2; i += 256){
    int g = i*2;
    int k = g / OUT, n = g % OUT;
    u32 v = *(const u32*)(Wb + (size_t)k*OUT + n);
    Wt[n*KP + k]     = (u16)(v & 0xffff);
    Wt[(n+1)*KP + k] = (u16)(v >> 16);
  }
  __syncthreads();

  const int wave = t >> 6, lane = t & 63;
  const int quad = lane >> 4, m16 = lane & 15;
  const int rowb = blockIdx.x*128 + wave*32;

  const short8 zz = {0,0,0,0,0,0,0,0};
  short8 afr[2][KS];
#pragma unroll
  for (int mt = 0; mt < 2; mt++){
    int row = rowb + mt*16 + m16;
    bool ok = row < nrows;
#pragma unroll
    for (int ks = 0; ks < KS; ks++){
      int k = ks*32 + quad*8;
      if (!ok){ afr[mt][ks] = zz; continue; }
      if constexpr (GATHER){
        int node, kk;
        if (k < 64){ node = uidx[row];      kk = k; }
        else       { node = nu + vidx[row]; kk = k - 64; }
        afr[mt][ks] = *(const short8*)(A + (size_t)node*64 + kk);
      } else {
        afr[mt][ks] = *(const short8*)(A + (size_t)row*K_ + k);
      }
    }
  }

  f32x4 acc[2][NT];
#pragma unroll
  for (int mt = 0; mt < 2; mt++)
#pragma unroll
    for (int nt = 0; nt < NT; nt++) acc[mt][nt] = (f32x4){0.f,0.f,0.f,0.f};

#pragma unroll
  for (int nt = 0; nt < NT; nt++){
#pragma unroll
    for (int ks = 0; ks < KS; ks++){
      short8 b = *(const short8*)(Wt + (size_t)(nt*16 + m16)*KP + ks*32 + quad*8);
      acc[0][nt] = __builtin_amdgcn_mfma_f32_16x16x32_bf16(afr[0][ks], b, acc[0][nt], 0, 0, 0);
      acc[1][nt] = __builtin_amdgcn_mfma_f32_16x16x32_bf16(afr[1][ks], b, acc[1][nt], 0, 0, 0);
    }
  }

  if constexpr (!DOTEP){
    float bv[NT];
#pragma unroll
    for (int nt = 0; nt < NT; nt++){
      if constexpr (BIAS) bv[nt] = bias[nt*16 + m16]; else bv[nt] = 0.f;
    }
#pragma unroll
    for (int mt = 0; mt < 2; mt++){
      int row0 = rowb + mt*16 + quad*4;
#pragma unroll
      for (int reg = 0; reg < 4; reg++){
        int row = row0 + reg;
        if (row >= nrows) continue;
        float rs = 1.f;
        if constexpr (SCALE) rs = rr[row];
#pragma unroll
        for (int nt = 0; nt < NT; nt++){
          float v = acc[mt][nt][reg];
          if constexpr (BIAS) v += bv[nt];
          if constexpr (RELU) v = fmaxf(v, 0.f);
          if constexpr (SCALE) v *= rs;
          C[(size_t)row*OUT + nt*16 + m16] = f2b(v);
        }
      }
    }
  } else {
    float b0 = bias[m16], b1v = bias[16 + m16];
    float p0 = P3[m16],   p1 = P3[16 + m16];
    float pb = pb3[0];
#pragma unroll
    for (int mt = 0; mt < 2; mt++){
      float v4[4];
#pragma unroll
      for (int reg = 0; reg < 4; reg++){
        float part = fmaxf(acc[mt][0][reg] + b0, 0.f) * p0
                   + fmaxf(acc[mt][1][reg] + b1v, 0.f) * p1;
        part += __shfl_xor(part, 1);
        part += __shfl_xor(part, 2);
        part += __shfl_xor(part, 4);
        part += __shfl_xor(part, 8);
        v4[reg] = 1.f / (1.f + __expf(-(part + pb)));
      }
      if (m16 == 0){
        int row0 = rowb + mt*16 + quad*4;
        if (row0 + 3 < nrows){
          *(float4*)(outp + row0) = make_float4(v4[0], v4[1], v4[2], v4[3]);
        } else {
#pragma unroll
          for (int reg = 0; reg < 4; reg++)
            if (row0 + reg < nrows) outp[row0 + reg] = v4[reg];
        }
      }
    }
  }
}

// ---------------- launcher ----------------

extern "C" void kernel_launch(void* const* d_in, const int* in_sizes, int n_in,
                              void* d_out, int out_size, void* d_ws, size_t ws_size,
                              hipStream_t stream){
  const float* ut  = (const float*)d_in[0];
  const float* it  = (const float*)d_in[1];
  const float* W1  = (const float*)d_in[2];
  const float* b1  = (const float*)d_in[3];
  const float* W2  = (const float*)d_in[4];
  const float* b2  = (const float*)d_in[5];
  const float* W3  = (const float*)d_in[6];
  const float* b3  = (const float*)d_in[7];
  const float* P1  = (const float*)d_in[8];
  const float* pb1 = (const float*)d_in[9];
  const float* P2  = (const float*)d_in[10];
  const float* pb2 = (const float*)d_in[11];
  const float* P3  = (const float*)d_in[12];
  const float* pb3 = (const float*)d_in[13];
  const int* src  = (const int*)d_in[14];
  const int* dst  = (const int*)d_in[15];
  const int* uidx = (const int*)d_in[16];
  const int* vidx = (const int*)d_in[17];

  const int NU = in_sizes[0] / 64;
  const int NI = in_sizes[1] / 64;
  const int N  = NU + NI;
  const int NE = in_sizes[14];
  const int B  = in_sizes[16];
  const int K  = (N + 255) >> 8;

  char* w = (char*)d_ws;
  auto alloc = [&](size_t bytes)->void*{
    void* p = (void*)w;
    w += (bytes + 255) & ~(size_t)255;
    return p;
  };
  float* r       = (float*)alloc((size_t)N*4);
  int*   row_ptr = (int*)  alloc((size_t)(N+1)*4);
  u32*   bhist   = (u32*)  alloc((size_t)K*4);
  u32*   bbase   = (u32*)  alloc((size_t)(K+1)*4);
  u32*   gcur    = (u32*)  alloc((size_t)K*4);
  int*   col     = (int*)  alloc((size_t)NE*4);
  u16*   Wall    = (u16*)  alloc((size_t)(64*128 + 128*128 + 128*64 + 128*64 + 64*32)*2);
  char*  bufE    = (char*) alloc((size_t)N*64*2 > (size_t)NE*4 ? (size_t)N*64*2 : (size_t)NE*4);
                                                      // ebuf(u32,NE) -> m1(bf16) -> x3(bf16)
  char*  bufF    = (char*) alloc((size_t)N*128*2);    // m2(bf16) -> A1(bf16, B*64)
  u16*   bufC    = (u16*)  alloc((size_t)N*128*2);    // h1 -> h2
  u16*   bufD    = (u16*)  alloc((size_t)N*64*2);     // x0 -> g3
  if ((size_t)(w - (char*)d_ws) > ws_size) return;

  u16* wb1  = Wall;                    // 64*128
  u16* wb2  = wb1 + 64*128;            // 128*128
  u16* wb3  = wb2 + 128*128;           // 128*64
  u16* pb1w = wb3 + 128*64;            // 128*64
  u16* pb2w = pb1w + 128*64;           // 64*32
  const int NW = 64*128 + 128*128 + 128*64 + 128*64 + 64*32;

  u32* ebuf = (u32*)bufE;

  hipMemsetAsync(bhist, 0, (size_t)K*4, stream);

  int g;
  k_cvtW   <<<(NW + 255)/256, 256, 0, stream>>>(W1, W2, W3, P1, P2,
              64*128, 128*128, 128*64, 128*64, 64*32, Wall);
  k_histK  <<<128, 256, (size_t)K*4, stream>>>(dst, NE, K, bhist);
  k_scanK  <<<1, 256, 0, stream>>>(bhist, K, bbase, gcur);
  g = (NE + 4095)/4096;
  k_scatterR<<<g, 256, (size_t)K*4, stream>>>(src, dst, NE, K, gcur, ebuf);
  k_csr    <<<K, 256, 0, stream>>>(ebuf, bbase, N, NE, row_ptr, r, col);

  const int ga  = (N + 3)/4;
  const int gN  = (N + 127)/128;
  const int gB  = (B + 127)/128;

  u16* x0 = bufD;
  g = (N*64/4 + 255)/256; k_scale0<<<g,256,0,stream>>>(ut, it, r, x0, N, NU);

  u16* m1 = (u16*)bufE;               // ebuf dead after k_csr
  k_agg<64,false><<<ga,256,0,stream>>>(x0, r, row_ptr, col, nullptr, m1, N);
  u16* h1 = bufC;
  k_mgemm<64,128,true,true,true,false,false><<<gN,256,0,stream>>>(
      m1, wb1, b1, r, h1, N, NU, nullptr, nullptr, nullptr, nullptr, nullptr);

  u16* m2 = (u16*)bufF;
  k_agg<128,false><<<ga,256,0,stream>>>(h1, r, row_ptr, col, nullptr, m2, N);
  u16* h2 = bufC;                     // h1 dead after agg
  k_mgemm<128,128,true,true,true,false,false><<<gN,256,0,stream>>>(
      m2, wb2, b2, r, h2, N, NU, nullptr, nullptr, nullptr, nullptr, nullptr);

  u16* g3 = bufD;                     // x0 dead after first agg
  k_mgemm<128,64,false,false,false,false,false><<<gN,256,0,stream>>>(
      h2, wb3, nullptr, nullptr, g3, N, NU, nullptr, nullptr, nullptr, nullptr, nullptr);

  u16* x3 = (u16*)bufE;               // m1 dead after GEMM1
  k_agg<64,true><<<ga,256,0,stream>>>(g3, r, row_ptr, col, b3, x3, N);

  u16* A1 = (u16*)bufF;               // m2 dead after GEMM2
  k_mgemm<128,64,true,true,false,true,false><<<gB,256,0,stream>>>(
      x3, pb1w, pb1, nullptr, A1, B, NU, uidx, vidx, nullptr, nullptr, nullptr);

  k_mgemm<64,32,true,true,false,false,true><<<gB,256,0,stream>>>(
      A1, pb2w, pb2, nullptr, nullptr, B, 0, nullptr, nullptr, P3, pb3, (float*)d_out);
}

// Round 9
// 488.489 us; speedup vs baseline: 2.5266x; 1.0253x over previous
//
#include <hip/hip_runtime.h>
#include <hip/hip_bf16.h>

// f32 in/out. All intermediates bf16 (f32 accumulation). GEMMs = MFMA
// 16x16x32_bf16 (round 7). Aggs: 2-edge unroll (2x outstanding gather chains,
// bit-identical accumulation order). Round-8 lesson: fdot2_f32_bf16's internal
// rounding tripled end-to-end error (0.0039 -> 0.0117 > 0.0103 threshold) --
// edge-sum must stay exact unpack + v_add_f32. CSR: block-aggregated
// reservation scatter (round 5).

typedef unsigned short u16;
typedef unsigned int   u32;
typedef __attribute__((ext_vector_type(8))) short short8;
typedef __attribute__((ext_vector_type(4))) float f32x4;

__device__ __forceinline__ float b2f(u16 u){
  union { u32 i; float f; } c; c.i = ((u32)u) << 16; return c.f;
}
__device__ __forceinline__ u16 f2b(float f){
  union { float f; u32 i; } c; c.f = f;
  u32 x = c.i;
  u32 r = x + 0x7FFFu + ((x >> 16) & 1u);   // round-to-nearest-even
  return (u16)(r >> 16);
}

// exact bf16-pair accumulate: a[0..7] += dims of uint4 (8 bf16)
__device__ __forceinline__ void acc8(uint4 u, float* a){
  a[0] += b2f((u16)(u.x & 0xffff)); a[1] += b2f((u16)(u.x >> 16));
  a[2] += b2f((u16)(u.y & 0xffff)); a[3] += b2f((u16)(u.y >> 16));
  a[4] += b2f((u16)(u.z & 0xffff)); a[5] += b2f((u16)(u.z >> 16));
  a[6] += b2f((u16)(u.w & 0xffff)); a[7] += b2f((u16)(u.w >> 16));
}

// ---------------- graph preprocessing: aggregated bucket scatter ----------------

__global__ __launch_bounds__(256) void k_histK(const int* __restrict__ dst, int ne, int K,
                                               u32* __restrict__ bhist){
  extern __shared__ u32 sh[];
  int t = threadIdx.x;
  for (int i = t; i < K; i += 256) sh[i] = 0;
  __syncthreads();
  for (int i = blockIdx.x*256 + t; i < ne; i += gridDim.x*256)
    atomicAdd(&sh[dst[i] >> 8], 1u);
  __syncthreads();
  int rot = (int)((blockIdx.x * 73u) % (u32)K);
  for (int jj = t; jj < K; jj += 256){
    int i = jj + rot; if (i >= K) i -= K;
    u32 v = sh[i];
    if (v) atomicAdd(&bhist[i], v);
  }
}

__global__ __launch_bounds__(256) void k_scanK(const u32* __restrict__ bhist, int K,
                                               u32* __restrict__ bbase, u32* __restrict__ gcur){
  __shared__ u32 s[256];
  int t = threadIdx.x;
  int items = (K + 255) / 256;
  u32 local[16];
  int s0 = t * items;
  u32 sum = 0;
  for (int j = 0; j < items; j++){
    int idx = s0 + j;
    u32 v = (idx < K) ? bhist[idx] : 0;
    local[j] = v; sum += v;
  }
  s[t] = sum; __syncthreads();
  for (int off = 1; off < 256; off <<= 1){
    u32 add = (t >= off) ? s[t-off] : 0;
    __syncthreads();
    s[t] += add;
    __syncthreads();
  }
  u32 run = s[t] - sum;
  for (int j = 0; j < items; j++){
    int idx = s0 + j;
    if (idx < K){ bbase[idx] = run; gcur[idx] = run; }
    run += local[j];
  }
  if (t == 255) bbase[K] = s[255];
}

__global__ __launch_bounds__(256) void k_scatterR(const int* __restrict__ src, const int* __restrict__ dst,
                                                  int ne, int K, u32* __restrict__ gcur,
                                                  u32* __restrict__ ebuf){
  extern __shared__ u32 cnt[];
  int t = threadIdx.x;
  int e0 = blockIdx.x * 4096;
  for (int i = t; i < K; i += 256) cnt[i] = 0;
  __syncthreads();
#pragma unroll
  for (int j = 0; j < 16; j++){
    int e = e0 + j*256 + t;
    if (e < ne) atomicAdd(&cnt[dst[e] >> 8], 1u);
  }
  __syncthreads();
  int rot = (int)((blockIdx.x * 73u) % (u32)K);
  for (int jj = t; jj < K; jj += 256){
    int i = jj + rot; if (i >= K) i -= K;
    u32 c = cnt[i];
    if (c) cnt[i] = atomicAdd(&gcur[i], c);
  }
  __syncthreads();
#pragma unroll
  for (int j = 0; j < 16; j++){
    int e = e0 + j*256 + t;
    if (e < ne){
      int d = dst[e];
      u32 p = atomicAdd(&cnt[d >> 8], 1u);
      ebuf[p] = ((u32)(d & 255) << 18) | (u32)src[e];
    }
  }
}

__global__ __launch_bounds__(256) void k_csr(const u32* __restrict__ ebuf, const u32* __restrict__ bbase,
                                             int n, int ne, int* __restrict__ row_ptr,
                                             float* __restrict__ r, int* __restrict__ col){
  __shared__ u32 cnt[256];
  __shared__ u32 pfx[256];
  __shared__ u32 cur[256];
  int b = blockIdx.x, t = threadIdx.x;
  u32 bb = bbase[b], be = bbase[b+1];
  int nbase = b << 8;
  int nn = n - nbase; if (nn > 256) nn = 256;
  cnt[t] = 0;
  __syncthreads();
  for (u32 e = bb + t; e < be; e += 256)
    atomicAdd(&cnt[ebuf[e] >> 18], 1u);
  __syncthreads();
  pfx[t] = cnt[t];
  __syncthreads();
  for (int off = 1; off < 256; off <<= 1){
    u32 add = (t >= off) ? pfx[t-off] : 0;
    __syncthreads();
    pfx[t] += add;
    __syncthreads();
  }
  u32 excl = pfx[t] - cnt[t];
  cur[t] = bb + excl;
  if (t < nn){
    row_ptr[nbase + t] = (int)(bb + excl);
    r[nbase + t] = rsqrtf(fmaxf((float)cnt[t], 1.0f));
  }
  __syncthreads();
  for (u32 e = bb + t; e < be; e += 256){
    u32 v = ebuf[e];
    u32 p = atomicAdd(&cur[v >> 18], 1u);
    col[p] = (int)(v & 0x3FFFFu);
  }
  if (b == 0 && t == 0) row_ptr[n] = ne;
}

// convert the 5 weight matrices f32 -> bf16 into one concatenated buffer
__global__ __launch_bounds__(256) void k_cvtW(const float* __restrict__ a0, const float* __restrict__ a1,
    const float* __restrict__ a2, const float* __restrict__ a3, const float* __restrict__ a4,
    int n0, int n1, int n2, int n3, int n4, u16* __restrict__ out){
  int i = blockIdx.x*256 + threadIdx.x;
  int idx = i;
  const float* s;
  if (idx < n0){ s = a0; }
  else { idx -= n0;
    if (idx < n1){ s = a1; }
    else { idx -= n1;
      if (idx < n2){ s = a2; }
      else { idx -= n2;
        if (idx < n3){ s = a3; }
        else { idx -= n3;
          if (idx >= n4) return;
          s = a4;
        }
      }
    }
  }
  out[i] = f2b(s[idx]);
}

// x0[n,64] (bf16) = concat(ut,it)[n,:] * r[n]
__global__ __launch_bounds__(256) void k_scale0(const float* __restrict__ ut, const float* __restrict__ it,
    const float* __restrict__ r, u16* __restrict__ x0, int n, int nu){
  int i = blockIdx.x*256 + threadIdx.x;
  int base = i*4;
  if (base < n*64){
    int node = base >> 6;
    float rv = r[node];
    const float* srcp = (node < nu) ? (ut + (size_t)node*64) : (it + (size_t)(node-nu)*64);
    float4 v = *(const float4*)(srcp + (base & 63));
    ushort4 o;
    o.x = f2b(v.x*rv); o.y = f2b(v.y*rv); o.z = f2b(v.z*rv); o.w = f2b(v.w*rv);
    *(ushort4*)(x0 + base) = o;
  }
}

// ---------------- aggregation: one wave per node, G-lane edge groups ----------------
// G = D/8 lanes per edge (uint4 = 8 bf16). E = 64/G edge groups; 2-edge unroll
// -> 2E gather chains in flight per wave. Exact unpack+add accumulate.
template<int D, bool BIAS>
__global__ __launch_bounds__(256) void k_agg(const u16* __restrict__ x, const float* __restrict__ r,
    const int* __restrict__ row_ptr, const int* __restrict__ col,
    const float* __restrict__ bias, u16* __restrict__ out, int n){
  constexpr int G = D/8;
  constexpr int E = 64/G;
  int wid = (blockIdx.x*256 + threadIdx.x) >> 6;
  int lane = threadIdx.x & 63;
  if (wid >= n) return;
  int gidx = lane / G;
  int l    = lane % G;
  int beg = row_ptr[wid], end = row_ptr[wid+1];
  float a[8] = {0.f,0.f,0.f,0.f,0.f,0.f,0.f,0.f};
  int e = beg + gidx;
  for (; e + E < end; e += 2*E){
    int s0 = col[e];
    int s1 = col[e+E];
    uint4 u0 = *(const uint4*)(x + (size_t)s0*D + l*8);
    uint4 u1 = *(const uint4*)(x + (size_t)s1*D + l*8);
    acc8(u0, a);
    acc8(u1, a);
  }
  if (e < end){
    int s = col[e];
    acc8(*(const uint4*)(x + (size_t)s*D + l*8), a);
  }
#pragma unroll
  for (int off = G; off < 64; off <<= 1){
#pragma unroll
    for (int i = 0; i < 8; i++) a[i] += __shfl_xor(a[i], off);
  }
  if (gidx == 0){
    float rn = r[wid];
    float v[8];
#pragma unroll
    for (int i = 0; i < 8; i++){
      float y = a[i] * rn;
      if constexpr (BIAS) y += bias[l*8 + i];
      v[i] = y;
    }
    uint4 o;
    o.x = (u32)f2b(v[0]) | ((u32)f2b(v[1]) << 16);
    o.y = (u32)f2b(v[2]) | ((u32)f2b(v[3]) << 16);
    o.z = (u32)f2b(v[4]) | ((u32)f2b(v[5]) << 16);
    o.w = (u32)f2b(v[6]) | ((u32)f2b(v[7]) << 16);
    *(uint4*)(out + (size_t)wid*D + l*8) = o;
  }
}

// ---------------- MFMA GEMM: C[nrows,OUT] = act(A[nrows,K_] @ W + b) * r ----------------
// 256 thr = 4 waves; wave covers 32 rows (2 m-tiles), block 128 rows.
// A bf16 row-major, direct global->VGPR frags. W bf16 [K_,OUT], staged W^T in
// LDS (pad +8). GATHER: row k<64 from A[uidx]*64, k>=64 from A[(nu+vidx)]*64.
// DOTEP: OUT=32, relu -> dot P3 -> sigmoid -> f32 out.
template<int K_, int OUT, bool BIAS, bool RELU, bool SCALE, bool GATHER, bool DOTEP>
__global__ __launch_bounds__(256) void k_mgemm(
    const u16* __restrict__ A, const u16* __restrict__ Wb, const float* __restrict__ bias,
    const float* __restrict__ rr, u16* __restrict__ C, int nrows, int nu,
    const int* __restrict__ uidx, const int* __restrict__ vidx,
    const float* __restrict__ P3, const float* __restrict__ pb3, float* __restrict__ outp)
{
  constexpr int KP = K_ + 8;
  constexpr int NT = OUT / 16;
  constexpr int KS = K_ / 32;
  __shared__ u16 Wt[OUT * KP];
  const int t = threadIdx.x;

  for (int i = t; i < (K_*OUT)/2; i += 256){
    int g = i*2;
    int k = g / OUT, n = g % OUT;
    u32 v = *(const u32*)(Wb + (size_t)k*OUT + n);
    Wt[n*KP + k]     = (u16)(v & 0xffff);
    Wt[(n+1)*KP + k] = (u16)(v >> 16);
  }
  __syncthreads();

  const int wave = t >> 6, lane = t & 63;
  const int quad = lane >> 4, m16 = lane & 15;
  const int rowb = blockIdx.x*128 + wave*32;

  const short8 zz = {0,0,0,0,0,0,0,0};
  short8 afr[2][KS];
#pragma unroll
  for (int mt = 0; mt < 2; mt++){
    int row = rowb + mt*16 + m16;
    bool ok = row < nrows;
#pragma unroll
    for (int ks = 0; ks < KS; ks++){
      int k = ks*32 + quad*8;
      if (!ok){ afr[mt][ks] = zz; continue; }
      if constexpr (GATHER){
        int node, kk;
        if (k < 64){ node = uidx[row];      kk = k; }
        else       { node = nu + vidx[row]; kk = k - 64; }
        afr[mt][ks] = *(const short8*)(A + (size_t)node*64 + kk);
      } else {
        afr[mt][ks] = *(const short8*)(A + (size_t)row*K_ + k);
      }
    }
  }

  f32x4 acc[2][NT];
#pragma unroll
  for (int mt = 0; mt < 2; mt++)
#pragma unroll
    for (int nt = 0; nt < NT; nt++) acc[mt][nt] = (f32x4){0.f,0.f,0.f,0.f};

#pragma unroll
  for (int nt = 0; nt < NT; nt++){
#pragma unroll
    for (int ks = 0; ks < KS; ks++){
      short8 b = *(const short8*)(Wt + (size_t)(nt*16 + m16)*KP + ks*32 + quad*8);
      acc[0][nt] = __builtin_amdgcn_mfma_f32_16x16x32_bf16(afr[0][ks], b, acc[0][nt], 0, 0, 0);
      acc[1][nt] = __builtin_amdgcn_mfma_f32_16x16x32_bf16(afr[1][ks], b, acc[1][nt], 0, 0, 0);
    }
  }

  if constexpr (!DOTEP){
    float bv[NT];
#pragma unroll
    for (int nt = 0; nt < NT; nt++){
      if constexpr (BIAS) bv[nt] = bias[nt*16 + m16]; else bv[nt] = 0.f;
    }
#pragma unroll
    for (int mt = 0; mt < 2; mt++){
      int row0 = rowb + mt*16 + quad*4;
#pragma unroll
      for (int reg = 0; reg < 4; reg++){
        int row = row0 + reg;
        if (row >= nrows) continue;
        float rs = 1.f;
        if constexpr (SCALE) rs = rr[row];
#pragma unroll
        for (int nt = 0; nt < NT; nt++){
          float v = acc[mt][nt][reg];
          if constexpr (BIAS) v += bv[nt];
          if constexpr (RELU) v = fmaxf(v, 0.f);
          if constexpr (SCALE) v *= rs;
          C[(size_t)row*OUT + nt*16 + m16] = f2b(v);
        }
      }
    }
  } else {
    float b0 = bias[m16], b1v = bias[16 + m16];
    float p0 = P3[m16],   p1 = P3[16 + m16];
    float pb = pb3[0];
#pragma unroll
    for (int mt = 0; mt < 2; mt++){
      float v4[4];
#pragma unroll
      for (int reg = 0; reg < 4; reg++){
        float part = fmaxf(acc[mt][0][reg] + b0, 0.f) * p0
                   + fmaxf(acc[mt][1][reg] + b1v, 0.f) * p1;
        part += __shfl_xor(part, 1);
        part += __shfl_xor(part, 2);
        part += __shfl_xor(part, 4);
        part += __shfl_xor(part, 8);
        v4[reg] = 1.f / (1.f + __expf(-(part + pb)));
      }
      if (m16 == 0){
        int row0 = rowb + mt*16 + quad*4;
        if (row0 + 3 < nrows){
          *(float4*)(outp + row0) = make_float4(v4[0], v4[1], v4[2], v4[3]);
        } else {
#pragma unroll
          for (int reg = 0; reg < 4; reg++)
            if (row0 + reg < nrows) outp[row0 + reg] = v4[reg];
        }
      }
    }
  }
}

// ---------------- launcher ----------------

extern "C" void kernel_launch(void* const* d_in, const int* in_sizes, int n_in,
                              void* d_out, int out_size, void* d_ws, size_t ws_size,
                              hipStream_t stream){
  const float* ut  = (const float*)d_in[0];
  const float* it  = (const float*)d_in[1];
  const float* W1  = (const float*)d_in[2];
  const float* b1  = (const float*)d_in[3];
  const float* W2  = (const float*)d_in[4];
  const float* b2  = (const float*)d_in[5];
  const float* W3  = (const float*)d_in[6];
  const float* b3  = (const float*)d_in[7];
  const float* P1  = (const float*)d_in[8];
  const float* pb1 = (const float*)d_in[9];
  const float* P2  = (const float*)d_in[10];
  const float* pb2 = (const float*)d_in[11];
  const float* P3  = (const float*)d_in[12];
  const float* pb3 = (const float*)d_in[13];
  const int* src  = (const int*)d_in[14];
  const int* dst  = (const int*)d_in[15];
  const int* uidx = (const int*)d_in[16];
  const int* vidx = (const int*)d_in[17];

  const int NU = in_sizes[0] / 64;
  const int NI = in_sizes[1] / 64;
  const int N  = NU + NI;
  const int NE = in_sizes[14];
  const int B  = in_sizes[16];
  const int K  = (N + 255) >> 8;

  char* w = (char*)d_ws;
  auto alloc = [&](size_t bytes)->void*{
    void* p = (void*)w;
    w += (bytes + 255) & ~(size_t)255;
    return p;
  };
  float* r       = (float*)alloc((size_t)N*4);
  int*   row_ptr = (int*)  alloc((size_t)(N+1)*4);
  u32*   bhist   = (u32*)  alloc((size_t)K*4);
  u32*   bbase   = (u32*)  alloc((size_t)(K+1)*4);
  u32*   gcur    = (u32*)  alloc((size_t)K*4);
  int*   col     = (int*)  alloc((size_t)NE*4);
  u16*   Wall    = (u16*)  alloc((size_t)(64*128 + 128*128 + 128*64 + 128*64 + 64*32)*2);
  char*  bufE    = (char*) alloc((size_t)N*64*2 > (size_t)NE*4 ? (size_t)N*64*2 : (size_t)NE*4);
                                                      // ebuf(u32,NE) -> m1(bf16) -> x3(bf16)
  char*  bufF    = (char*) alloc((size_t)N*128*2);    // m2(bf16) -> A1(bf16, B*64)
  u16*   bufC    = (u16*)  alloc((size_t)N*128*2);    // h1 -> h2
  u16*   bufD    = (u16*)  alloc((size_t)N*64*2);     // x0 -> g3
  if ((size_t)(w - (char*)d_ws) > ws_size) return;

  u16* wb1  = Wall;                    // 64*128
  u16* wb2  = wb1 + 64*128;            // 128*128
  u16* wb3  = wb2 + 128*128;           // 128*64
  u16* pb1w = wb3 + 128*64;            // 128*64
  u16* pb2w = pb1w + 128*64;           // 64*32
  const int NW = 64*128 + 128*128 + 128*64 + 128*64 + 64*32;

  u32* ebuf = (u32*)bufE;

  hipMemsetAsync(bhist, 0, (size_t)K*4, stream);

  int g;
  k_cvtW   <<<(NW + 255)/256, 256, 0, stream>>>(W1, W2, W3, P1, P2,
              64*128, 128*128, 128*64, 128*64, 64*32, Wall);
  k_histK  <<<128, 256, (size_t)K*4, stream>>>(dst, NE, K, bhist);
  k_scanK  <<<1, 256, 0, stream>>>(bhist, K, bbase, gcur);
  g = (NE + 4095)/4096;
  k_scatterR<<<g, 256, (size_t)K*4, stream>>>(src, dst, NE, K, gcur, ebuf);
  k_csr    <<<K, 256, 0, stream>>>(ebuf, bbase, N, NE, row_ptr, r, col);

  const int ga  = (N + 3)/4;
  const int gN  = (N + 127)/128;
  const int gB  = (B + 127)/128;

  u16* x0 = bufD;
  g = (N*64/4 + 255)/256; k_scale0<<<g,256,0,stream>>>(ut, it, r, x0, N, NU);

  u16* m1 = (u16*)bufE;               // ebuf dead after k_csr
  k_agg<64,false><<<ga,256,0,stream>>>(x0, r, row_ptr, col, nullptr, m1, N);
  u16* h1 = bufC;
  k_mgemm<64,128,true,true,true,false,false><<<gN,256,0,stream>>>(
      m1, wb1, b1, r, h1, N, NU, nullptr, nullptr, nullptr, nullptr, nullptr);

  u16* m2 = (u16*)bufF;
  k_agg<128,false><<<ga,256,0,stream>>>(h1, r, row_ptr, col, nullptr, m2, N);
  u16* h2 = bufC;                     // h1 dead after agg
  k_mgemm<128,128,true,true,true,false,false><<<gN,256,0,stream>>>(
      m2, wb2, b2, r, h2, N, NU, nullptr, nullptr, nullptr, nullptr, nullptr);

  u16* g3 = bufD;                     // x0 dead after first agg
  k_mgemm<128,64,false,false,false,false,false><<<gN,256,0,stream>>>(
      h2, wb3, nullptr, nullptr, g3, N, NU, nullptr, nullptr, nullptr, nullptr, nullptr);

  u16* x3 = (u16*)bufE;               // m1 dead after GEMM1
  k_agg<64,true><<<ga,256,0,stream>>>(g3, r, row_ptr, col, b3, x3, N);

  u16* A1 = (u16*)bufF;               // m2 dead after GEMM2
  k_mgemm<128,64,true,true,false,true,false><<<gB,256,0,stream>>>(
      x3, pb1w, pb1, nullptr, A1, B, NU, uidx, vidx, nullptr, nullptr, nullptr);

  k_mgemm<64,32,true,true,false,false,true><<<gB,256,0,stream>>>(
      A1, pb2w, pb2, nullptr, nullptr, B, 0, nullptr, nullptr, P3, pb3, (float*)d_out);
}